// Round 9
// baseline (253.438 us; speedup 1.0000x reference)
//
#include <hip/hip_runtime.h>
#include <hip/hip_bf16.h>
#include <math.h>

// GRACE-style graph contrastive loss, MI355X (gfx950).
// R23: attack fm_k's fill role (42.7us at ~0% pipe util — latency/scatter
// bound). (1) edge payload (col,weight) packed into ONE int2 array: one 8B
// scattered store per edge instead of two 4B stores to different cache lines
// (halves dirtied lines; also halves index-stream loads in gg_k/pn_k gathers,
// which re-read ec/w 4x/16x per edge across their per-row thread groups).
// (2) fill grid-strided at 8 edges/thread (256 blocks): 8 independent
// load->atomicAdd->store chains per thread = ILP that the one-shot version
// lacked. Same values, same CSR-order accumulation. gram3 (R18), fused
// gather->pn, parallel rloss unchanged. Baseline: 247.1us.

#define NROWS 8192
#define MROWS 16384
#define NEDGE 262144
#define EPT 8                      // fill edges per thread
#define NFILLB (2*(NEDGE/(256*EPT)))   // 256 fill blocks

typedef __attribute__((ext_vector_type(8))) short bf16x8;
typedef __attribute__((ext_vector_type(4))) float f32x4;
typedef __attribute__((ext_vector_type(2))) float f32x2;
typedef __attribute__((ext_vector_type(8))) int i32x8;
typedef long long i64;

__device__ __forceinline__ short f2bf(float f){
  union { float f; unsigned u; } cv; cv.f = f;
  unsigned u = cv.u;
  unsigned r = (u + 0x7fffu + ((u >> 16) & 1u)) >> 16;  // RNE; inputs finite
  return (short)r;
}
__device__ __forceinline__ f32x4 mfma16(bf16x8 a, bf16x8 b, f32x4 c){
  return __builtin_amdgcn_mfma_f32_16x16x32_bf16(a, b, c, 0, 0, 0);
}
__device__ __forceinline__ float fexp2(float x){
#if __has_builtin(__builtin_amdgcn_exp2f)
  return __builtin_amdgcn_exp2f(x);
#else
  return exp2f(x);
#endif
}

// DPP row_shl add: lane i += lane(i+N) within each 16-lane row (0 beyond row
// edge via bound_ctrl). Chain {1,2,4,8}: lane 0 of each row accumulates the
// balanced tree ((v0+v1)+(v2+v3))+... == xor butterfly's lane-0 result.
template<int CTRL>
__device__ __forceinline__ float dpp_add(float v){
  int s = __builtin_amdgcn_update_dpp(0, __builtin_bit_cast(int, v),
                                      CTRL, 0xf, 0xf, true);
  return v + __builtin_bit_cast(float, s);
}
__device__ __forceinline__ float red16(float v){
  v = dpp_add<0x101>(v);   // row_shl:1
  v = dpp_add<0x102>(v);   // row_shl:2
  v = dpp_add<0x104>(v);   // row_shl:4
  v = dpp_add<0x108>(v);   // row_shl:8
  return v;
}

// ---- fp8 e4m3fn pack (RNE) ----
__device__ unsigned char f2e4m3_sw(float f){
  float a = fabsf(f);
  unsigned s = (__float_as_uint(f)>>24)&0x80u;
  if (!(a>0.f)) return (unsigned char)s;
  if (a>448.f) a=448.f;
  int e; frexpf(a,&e);
  int eff=e-1;
  unsigned code;
  if (eff<-6){
    float q=rintf(a*512.f);
    code=(unsigned)q; if(code>7)code=7;
  } else {
    float q=rintf(a*exp2f((float)(3-eff)));
    unsigned mant=(unsigned)q;
    if(mant>=16){mant=8;eff++;}
    if(eff>8) return (unsigned char)(s|0x7e);
    code=((unsigned)(eff+7)<<3)|(mant-8);
  }
  return (unsigned char)(s|code);
}
__device__ __forceinline__ unsigned short pack2fp8(float a, float b){
#if __has_builtin(__builtin_amdgcn_cvt_pk_fp8_f32)
  int v = __builtin_amdgcn_cvt_pk_fp8_f32(a, b, 0, false);
  return (unsigned short)(v & 0xffff);
#else
  return (unsigned short)((unsigned)f2e4m3_sw(a) | ((unsigned)f2e4m3_sw(b)<<8));
#endif
}

// ---- setup: weight transpose+bf16 (6 weights) | degree histogram ----
struct WtArgs {
  const float* src[6];
  short* dst[6];
  int K[6], N[6];
  int off[7];
  int nwt;
};
__global__ void setup_k(WtArgs a, const int* __restrict__ ei1, const int* __restrict__ ei2,
                        int* __restrict__ deg1, int* __restrict__ deg2){
  int b = blockIdx.x;
  if (b < a.nwt){
    int i = b*256 + threadIdx.x;
    if (i >= a.off[6]) return;
    int s = 0;
    #pragma unroll
    for (int j=1;j<6;j++) if (i >= a.off[j]) s=j;
    int l = i - a.off[s];
    int K=a.K[s], N=a.N[s];
    int k=l/N, n=l-k*N;
    a.dst[s][(long)n*K+k] = f2bf(a.src[s][l]);
  } else {
    int hb = b - a.nwt;
    const int* ei = (hb < NEDGE/256) ? ei1 : ei2;
    int* deg = (hb < NEDGE/256) ? deg1 : deg2;
    int e = (hb % (NEDGE/256))*256 + threadIdx.x;
    atomicAdd(&deg[ei[e]], 1);
  }
}

// ---- CSR build: scan ----
__global__ void scan2_k(const int* __restrict__ deg1, int* __restrict__ rs1, int* __restrict__ cur1,
                        const int* __restrict__ deg2, int* __restrict__ rs2, int* __restrict__ cur2){
  const int* deg = blockIdx.x ? deg2 : deg1;
  int* rowstart = blockIdx.x ? rs2 : rs1;
  int* cursor = blockIdx.x ? cur2 : cur1;
  __shared__ int csum[256];
  int t = threadIdx.x;
  int loc[32];
  int s = 0;
  for (int j=0;j<32;j++){ int d = deg[t*32+j]; loc[j] = s; s += d; }
  // inclusive Hillis-Steele scan of per-thread totals
  int v = s;
  csum[t] = v;
  __syncthreads();
  for (int st=1; st<256; st<<=1){
    int o = (t >= st) ? csum[t-st] : 0;
    __syncthreads();
    v += o;
    csum[t] = v;
    __syncthreads();
  }
  int base = v - s;   // exclusive prefix for this thread's 32 rows
  for (int j=0;j<32;j++){ int w = base + loc[j]; rowstart[t*32+j]=w; cursor[t*32+j]=w; }
  if (t==255) rowstart[NROWS] = v;
}

// ---- fm_k: CSR fill (blocks 0..NFILLB-1, grid-strided 8 edges/thread,
// packed int2 payload) fused with mlp12 (remaining 512 blocks). ----
__global__ __launch_bounds__(256) void fm_k(const float* __restrict__ F0, const float* __restrict__ F1,
    const short* __restrict__ Wa, const float* __restrict__ ba,
    const short* __restrict__ Wb, const float* __restrict__ bb, short* __restrict__ xb,
    const int* __restrict__ ei1, const float* __restrict__ w1, int* __restrict__ cur1,
    int2* __restrict__ eg1,
    const int* __restrict__ ei2, const float* __restrict__ w2, int* __restrict__ cur2,
    int2* __restrict__ eg2){
  __shared__ short As[32*520];   // 32x512 bf16, +8 pad
  __shared__ short a1s[32*72];   // 32x64 bf16, +8 pad
  const int tid = threadIdx.x;
  if (blockIdx.x < NFILLB){
    // ---- CSR fill role: 8 independent edges/thread (ILP latency hiding) ----
    int b = blockIdx.x;
    bool g2 = (b >= NFILLB/2);
    const int* ei = g2 ? ei2 : ei1;
    const float* w = g2 ? w2 : w1;
    int* cursor = g2 ? cur2 : cur1;
    int2* eg = g2 ? eg2 : eg1;
    int e0 = (b % (NFILLB/2))*(256*EPT) + tid;
    int r[EPT]; int c[EPT]; float wv[EPT];
    #pragma unroll
    for (int u=0;u<EPT;u++){
      int e = e0 + u*256;
      r[u] = ei[e];
      c[u] = ei[NEDGE + e];
      wv[u] = w[e];
    }
    int p[EPT];
    #pragma unroll
    for (int u=0;u<EPT;u++) p[u] = atomicAdd(&cursor[r[u]], 1);
    #pragma unroll
    for (int u=0;u<EPT;u++) eg[p[u]] = make_int2(c[u], __float_as_int(wv[u]));
    return;
  }
  // ---- mlp12 role: xb[M,32] = (relu(feat@Wa+ba))@Wb+bb, 32 rows/block ----
  const int m0 = (blockIdx.x - NFILLB)*32;
  const float* F = (m0 < NROWS) ? (F0 + (long)m0*512) : (F1 + (long)(m0-NROWS)*512);
  {
    float4 st[16];
    #pragma unroll
    for (int i=0;i<16;i++) st[i] = *(const float4*)(F + (long)(i*256+tid)*4);
    #pragma unroll
    for (int i=0;i<16;i++){
      int idx = i*256+tid, row = idx>>7, c4 = idx&127;
      unsigned lo = (unsigned)(unsigned short)f2bf(st[i].x) | ((unsigned)(unsigned short)f2bf(st[i].y)<<16);
      unsigned hi = (unsigned)(unsigned short)f2bf(st[i].z) | ((unsigned)(unsigned short)f2bf(st[i].w)<<16);
      uint2 o = {lo, hi};
      *(uint2*)&As[row*520 + c4*4] = o;
    }
  }
  __syncthreads();
  const int wave = tid>>6, lane = tid&63, quad = lane>>4, cl = lane&15;
  f32x4 zero = {0.f,0.f,0.f,0.f};
  {
    // stage1: 32 rows (MT=2) x 16 cols per wave, K=512
    const int wno = wave*16;
    f32x4 acc[2] = {zero, zero};
    #pragma unroll
    for (int kc=0;kc<16;kc++){
      const int ko = kc*32 + quad*8;
      bf16x8 a0 = *(const bf16x8*)&As[(cl)*520 + ko];
      bf16x8 a1 = *(const bf16x8*)&As[(16+cl)*520 + ko];
      bf16x8 b = *(const bf16x8*)(Wa + (long)(wno + cl)*512 + ko);
      acc[0] = mfma16(a0, b, acc[0]);
      acc[1] = mfma16(a1, b, acc[1]);
    }
    int col = wno + cl;
    float bv = ba[col];
    #pragma unroll
    for (int mt=0;mt<2;mt++)
      #pragma unroll
      for (int r=0;r<4;r++)
        a1s[(mt*16 + quad*4 + r)*72 + col] = f2bf(fmaxf(acc[mt][r] + bv, 0.f));
  }
  __syncthreads();
  if (wave < 2){
    // stage2: wave w -> rows w*16..+15, full 32 cols (NT=2), K=64
    f32x4 acc2[2] = {zero, zero};
    #pragma unroll
    for (int kc=0;kc<2;kc++){
      const int ko = kc*32 + quad*8;
      bf16x8 a = *(const bf16x8*)&a1s[(wave*16+cl)*72 + ko];
      #pragma unroll
      for (int nt=0;nt<2;nt++){
        bf16x8 b = *(const bf16x8*)(Wb + (long)(nt*16 + cl)*64 + ko);
        acc2[nt] = mfma16(a, b, acc2[nt]);
      }
    }
    #pragma unroll
    for (int nt=0;nt<2;nt++){
      int col = nt*16 + cl;
      float bv = bb[col];
      #pragma unroll
      for (int r=0;r<4;r++)
        xb[(long)(m0 + wave*16 + quad*4 + r)*32 + col] = f2bf(acc2[nt][r] + bv);
    }
  }
}

// ---- gather helpers (packed int2 edges: x=col, y=weight bits) ----
__device__ __forceinline__ void acc8(float* acc, int4 v, float f){
  const unsigned* u = (const unsigned*)&v;
  #pragma unroll
  for (int i=0;i<4;i++){
    union{unsigned x; float y;} lo, hi;
    lo.x = u[i] << 16;
    hi.x = u[i] & 0xffff0000u;
    acc[2*i]   = fmaf(f, lo.y, acc[2*i]);
    acc[2*i+1] = fmaf(f, hi.y, acc[2*i+1]);
  }
}
template<int C>
__device__ __forceinline__ void gather_row(float* acc, const short* sb,
                                           const int2* eg, int s, int e){
  int k = s;
  for (; k+16 <= e; k+=16){
    int2 cw[16]; int4 v[16];
    #pragma unroll
    for (int u=0;u<16;u++) cw[u] = eg[k+u];
    #pragma unroll
    for (int u=0;u<16;u++) v[u] = *(const int4*)(sb + (long)cw[u].x*C);
    #pragma unroll
    for (int u=0;u<16;u++) acc8(acc, v[u], __int_as_float(cw[u].y));
  }
  for (; k+4 <= e; k+=4){
    int2 c0=eg[k], c1=eg[k+1], c2=eg[k+2], c3=eg[k+3];
    int4 v0 = *(const int4*)(sb + (long)c0.x*C);
    int4 v1 = *(const int4*)(sb + (long)c1.x*C);
    int4 v2 = *(const int4*)(sb + (long)c2.x*C);
    int4 v3 = *(const int4*)(sb + (long)c3.x*C);
    acc8(acc,v0,__int_as_float(c0.y)); acc8(acc,v1,__int_as_float(c1.y));
    acc8(acc,v2,__int_as_float(c2.y)); acc8(acc,v3,__int_as_float(c3.y));
  }
  for (; k < e; k++){
    int2 c0 = eg[k];
    int4 v0 = *(const int4*)(sb + (long)c0.x*C);
    acc8(acc,v0,__int_as_float(c0.y));
  }
}

// ---- gg_k: gather32 (adj@xb -> LDS) + g34 (relu(ax@Wg1+bg1)@Wg2 -> s2) ----
__global__ __launch_bounds__(256) void gg_k(const short* __restrict__ xb,
    const int* __restrict__ rs1, const int2* __restrict__ eg1,
    const int* __restrict__ rs2, const int2* __restrict__ eg2,
    const short* __restrict__ Wg1, const float* __restrict__ bg1,
    const short* __restrict__ Wg2, short* __restrict__ s2){
  __shared__ short axs[64*40];    // gathered ax tile (pad 8)
  __shared__ short hbs[64*264];   // relu(ax@Wg1+b) tile (pad 8)
  const int tid = threadIdx.x;
  const int m0 = blockIdx.x*64;
  {
    const int g = tid & 3, sub = tid >> 2;
    const int row = m0 + sub;
    const int* rs; const int2* eg; int soff, lr;
    if (row < NROWS){ rs=rs1; eg=eg1; soff=0; lr=row; }
    else            { rs=rs2; eg=eg2; soff=NROWS; lr=row-NROWS; }
    const short* sb = xb + (long)soff*32 + g*8;
    float acc[8];
    #pragma unroll
    for (int j=0;j<8;j++) acc[j] = 0.f;
    gather_row<32>(acc, sb, eg, rs[lr], rs[lr+1]);
    int4 ov;
    unsigned* ou = (unsigned*)&ov;
    #pragma unroll
    for (int i=0;i<4;i++)
      ou[i] = (unsigned)(unsigned short)f2bf(acc[2*i]) | ((unsigned)(unsigned short)f2bf(acc[2*i+1])<<16);
    *(int4*)&axs[sub*40 + g*8] = ov;
  }
  __syncthreads();
  const int wave = tid>>6, lane = tid&63, quad = lane>>4, cl = lane&15;
  f32x4 zero = {0.f,0.f,0.f,0.f};
  {
    const int wno = wave*64;
    f32x4 acc[4][4];
    #pragma unroll
    for (int i=0;i<4;i++)
      #pragma unroll
      for (int j=0;j<4;j++) acc[i][j]=zero;
    const int ko = quad*8;
    bf16x8 a[4], b[4];
    #pragma unroll
    for (int mt=0;mt<4;mt++)
      a[mt] = *(const bf16x8*)&axs[(mt*16+cl)*40 + ko];
    #pragma unroll
    for (int nt=0;nt<4;nt++)
      b[nt] = *(const bf16x8*)(Wg1 + (long)(wno + nt*16 + cl)*32 + ko);
    #pragma unroll
    for (int mt=0;mt<4;mt++)
      #pragma unroll
      for (int nt=0;nt<4;nt++)
        acc[mt][nt] = mfma16(a[mt], b[nt], acc[mt][nt]);
    #pragma unroll
    for (int nt=0;nt<4;nt++){
      int col = wno + nt*16 + cl;
      float bv = bg1[col];
      #pragma unroll
      for (int mt=0;mt<4;mt++)
        #pragma unroll
        for (int r=0;r<4;r++)
          hbs[(mt*16 + quad*4 + r)*264 + col] = f2bf(fmaxf(acc[mt][nt][r] + bv, 0.f));
    }
  }
  __syncthreads();
  {
    const int wno = wave*32;
    f32x4 acc[4][2];
    #pragma unroll
    for (int i=0;i<4;i++){ acc[i][0]=zero; acc[i][1]=zero; }
    #pragma unroll
    for (int kc=0;kc<8;kc++){
      const int ko = kc*32 + quad*8;
      bf16x8 a[4], b[2];
      #pragma unroll
      for (int mt=0;mt<4;mt++)
        a[mt] = *(const bf16x8*)&hbs[(mt*16+cl)*264 + ko];
      #pragma unroll
      for (int nt=0;nt<2;nt++)
        b[nt] = *(const bf16x8*)(Wg2 + (long)(wno + nt*16 + cl)*256 + ko);
      #pragma unroll
      for (int mt=0;mt<4;mt++)
        #pragma unroll
        for (int nt=0;nt<2;nt++)
          acc[mt][nt] = mfma16(a[mt], b[nt], acc[mt][nt]);
    }
    #pragma unroll
    for (int mt=0;mt<4;mt++)
      #pragma unroll
      for (int nt=0;nt<2;nt++){
        int col = wno + nt*16 + cl;
        #pragma unroll
        for (int r=0;r<4;r++)
          s2[(long)(m0 + mt*16 + quad*4 + r)*128 + col] = f2bf(acc[mt][nt][r]);
      }
  }
}

// ---- pn_k: layer-2 aggregation (gathered in-block) + proj1(elu) +
// proj2 + normalize + fp8-quantize, PAIR-ROW blocks. ----
__global__ __launch_bounds__(256) void pn_k(const short* __restrict__ s2,
    const int* __restrict__ rs1, const int2* __restrict__ eg1,
    const int* __restrict__ rs2, const int2* __restrict__ eg2,
    const float* __restrict__ bg2,
    const short* __restrict__ Wf1, const float* __restrict__ bf1,
    const short* __restrict__ Wf2, const float* __restrict__ bf2,
    unsigned short* __restrict__ Zf, float* __restrict__ bdot){
  __shared__ short hs[64*136];
  __shared__ short t2s[64*72];
  __shared__ float zs[64*132];
  __shared__ float sp[4][64];
  __shared__ float dp[4][32];
  __shared__ float rnS[64];
  const float SQKE = 1.6986436f;   // sqrt(2*log2(e))
  const int tid = threadIdx.x;
  const int wave = tid>>6, lane = tid&63, quad = lane>>4, cl = lane&15;
  const int m0h = blockIdx.x*32;
  {
    // gather 64 rows into hs: rows 0..31 = graph1, rows 32..63 = graph2.
    const int g = tid & 15, sub = tid >> 4;
    #pragma unroll 1
    for (int pass=0; pass<4; pass++){
      int hrow = pass*16 + sub;
      int lr = m0h + (hrow & 31);
      const int* rs; const int2* eg; long soff;
      if (hrow < 32){ rs=rs1; eg=eg1; soff=0; }
      else          { rs=rs2; eg=eg2; soff=NROWS; }
      const short* sb = s2 + soff*128 + g*8;
      float acc[8];
      #pragma unroll
      for (int j=0;j<8;j++) acc[j] = bg2[g*8+j];
      gather_row<128>(acc, sb, eg, rs[lr], rs[lr+1]);
      int4 ov;
      unsigned* ou = (unsigned*)&ov;
      #pragma unroll
      for (int i=0;i<4;i++)
        ou[i] = (unsigned)(unsigned short)f2bf(acc[2*i]) | ((unsigned)(unsigned short)f2bf(acc[2*i+1])<<16);
      *(int4*)&hs[hrow*136 + g*8] = ov;
    }
  }
  __syncthreads();
  f32x4 zero = {0.f,0.f,0.f,0.f};
  {
    // proj1: NN=64, K=128, elu -> t2s
    const int wno = wave*16;
    f32x4 acc[4];
    #pragma unroll
    for (int i=0;i<4;i++) acc[i]=zero;
    #pragma unroll
    for (int kc=0;kc<4;kc++){
      const int ko = kc*32 + quad*8;
      bf16x8 a[4], b;
      #pragma unroll
      for (int mt=0;mt<4;mt++)
        a[mt] = *(const bf16x8*)&hs[(mt*16+cl)*136 + ko];
      b = *(const bf16x8*)(Wf1 + (long)(wno + cl)*128 + ko);
      #pragma unroll
      for (int mt=0;mt<4;mt++) acc[mt] = mfma16(a[mt], b, acc[mt]);
    }
    int col = wno + cl;
    float bv = bf1[col];
    #pragma unroll
    for (int mt=0;mt<4;mt++)
      #pragma unroll
      for (int r=0;r<4;r++){
        float v = acc[mt][r] + bv;
        v = (v > 0.f) ? v : expm1f(v);
        t2s[(mt*16 + quad*4 + r)*72 + col] = f2bf(v);
      }
  }
  __syncthreads();
  {
    // proj2: NN=128, K=64 -> zs (fp32)
    const int wno = wave*32;
    f32x4 acc[4][2];
    #pragma unroll
    for (int i=0;i<4;i++){ acc[i][0]=zero; acc[i][1]=zero; }
    #pragma unroll
    for (int kc=0;kc<2;kc++){
      const int ko = kc*32 + quad*8;
      bf16x8 a[4], b[2];
      #pragma unroll
      for (int mt=0;mt<4;mt++)
        a[mt] = *(const bf16x8*)&t2s[(mt*16+cl)*72 + ko];
      #pragma unroll
      for (int nt=0;nt<2;nt++)
        b[nt] = *(const bf16x8*)(Wf2 + (long)(wno + nt*16 + cl)*64 + ko);
      #pragma unroll
      for (int mt=0;mt<4;mt++)
        #pragma unroll
        for (int nt=0;nt<2;nt++)
          acc[mt][nt] = mfma16(a[mt], b[nt], acc[mt][nt]);
    }
    #pragma unroll
    for (int mt=0;mt<4;mt++)
      #pragma unroll
      for (int nt=0;nt<2;nt++){
        int col = wno + nt*16 + cl;
        float bv = bf2[col];
        #pragma unroll
        for (int r=0;r<4;r++)
          zs[(mt*16 + quad*4 + r)*132 + col] = acc[mt][nt][r] + bv;
      }
  }
  __syncthreads();
  {
    int row = tid & 63, qtr = tid >> 6;
    const float* zr = &zs[row*132 + qtr*32];
    float s = 0.f;
    #pragma unroll 8
    for (int c=0;c<32;c++) s += zr[c]*zr[c];
    sp[qtr][row] = s;
    if (row < 32){
      const float* zb_ = &zs[(row+32)*132 + qtr*32];
      float d = 0.f;
      #pragma unroll 8
      for (int c=0;c<32;c++) d += zr[c]*zb_[c];
      dp[qtr][row] = d;
    }
  }
  __syncthreads();
  if (tid < 64){
    float ssq = sp[0][tid]+sp[1][tid]+sp[2][tid]+sp[3][tid];
    rnS[tid] = 1.f / fmaxf(sqrtf(ssq), 1e-12f);
  }
  __syncthreads();
  if (tid < 32){
    float dot = dp[0][tid]+dp[1][tid]+dp[2][tid]+dp[3][tid];
    bdot[m0h + tid] = dot * rnS[tid] * rnS[tid+32];
  }
  {
    // fp8*sqrt(KE) quantize into K=128 f8f6f4 fragment-order Zf.
    int lr = tid >> 2;
    int grow = (lr < 32) ? (m0h + lr) : (NROWS + m0h + lr - 32);
    float s = rnS[lr] * SQKE;
    int p0 = (tid & 3)*16;
    long gbase = (long)(grow>>4)*1024 + (long)(grow&15)*16 + (long)(p0>>4)*256;
    #pragma unroll
    for (int pp=0;pp<16;pp++){
      int p = p0 + pp;
      Zf[gbase + pp] = pack2fp8(zs[lr*132 + 2*p]*s, zs[lr*132 + 2*p + 1]*s);
    }
  }
}

// ---- symmetric exp-Gram partials (R18 form: single tile/wave, MX K=128
// MFMA scale=1.0, strip pipeline, DPP row_shl reduce; VGPR 60, no spill).
__global__ __launch_bounds__(256,4) void gram3_k(const unsigned char* __restrict__ Zf,
                                                 float* __restrict__ P){
  __shared__ float srow[4][64];
  __shared__ float scol[4][64];
  const int wave = threadIdx.x>>6, lane = threadIdx.x&63;
  const int t = blockIdx.x*4 + wave;           // UT tile index, T=256
  int ti = (int)((513.0f - sqrtf(513.0f*513.0f - 8.0f*(float)t))*0.5f);
  while ((ti+1)*256 - ((ti+1)*ti)/2 <= t) ti++;
  while (ti*256 - (ti*(ti-1))/2 > t) ti--;
  const int tj = ti + (t - (ti*256 - (ti*(ti-1))/2));
  // 64-row tile = 4 groups x 2048B; lane reads 32 contiguous K-bytes
  const unsigned char* za = Zf + (long)ti*8192 + lane*32;
  const unsigned char* zb = Zf + (long)tj*8192 + lane*32;
  const int quad = lane>>4, cl = lane&15;

  f32x4 zero = {0.f,0.f,0.f,0.f};
  f32x2 z2 = {0.f,0.f};
  f32x2 cs[4] = {z2,z2,z2,z2};

  // all B fragments resident: Bf[nt] (v8i32 each)
  i32x8 Bf[4];
  #pragma unroll
  for (int nt=0;nt<4;nt++)
    Bf[nt] = *(const i32x8*)(zb + nt*2048);

  // A double-buffer: strip mt lives in Ab[mt&1]
  i32x8 Ab[2];
  Ab[0] = *(const i32x8*)(za);
  Ab[1] = *(const i32x8*)(za + 2048);

  // exp + row-sum reduce of one 16-row strip; DPP row_shl tree (lane cl==0
  // result bit-identical to the xor butterfly's).
  auto exprow = [&](const f32x4* ar, int mt){
    f32x2 r01 = z2, r23 = z2;
    #pragma unroll
    for (int nt=0;nt<4;nt++){
      f32x4 v = ar[nt];
      float e0 = fexp2(v[0]), e1 = fexp2(v[1]);
      float e2 = fexp2(v[2]), e3 = fexp2(v[3]);
      f32x2 p01 = {e0,e1}, p23 = {e2,e3};
      r01 += p01; r23 += p23;
      cs[nt] += p01; cs[nt] += p23;
    }
    float s0 = red16(r01.x);
    float s1 = red16(r01.y);
    float s2 = red16(r23.x);
    float s3 = red16(r23.y);
    if (cl==0){
      f32x4 rv = {s0, s1, s2, s3};
      *(f32x4*)&srow[wave][mt*16 + quad*4] = rv;
    }
  };

  const int SC1 = 0x7F;   // e8m0 scale = 2^0
  f32x4 acc2[2][4];
  // strip 0: one K=128 MFMA per nt
  #pragma unroll
  for (int nt=0;nt<4;nt++)
    acc2[0][nt] = __builtin_amdgcn_mfma_scale_f32_16x16x128_f8f6f4(
        Ab[0], Bf[nt], zero, 0, 0, 0, SC1, 0, SC1);
  // strips 1..3: prefetch A, issue MFMAs, exp previous strip underneath
  #pragma unroll
  for (int mt=1; mt<4; mt++){
    const int cur = mt&1, prv = cur^1;
    if (mt<3)
      Ab[prv] = *(const i32x8*)(za + (mt+1)*2048);
    #pragma unroll
    for (int nt=0;nt<4;nt++)
      acc2[cur][nt] = __builtin_amdgcn_mfma_scale_f32_16x16x128_f8f6f4(
          Ab[cur], Bf[nt], zero, 0, 0, 0, SC1, 0, SC1);
    exprow(&acc2[prv][0], mt-1);
  }
  exprow(&acc2[1][0], 3);

  __threadfence_block();
  P[((long)ti*256 + tj)*64 + lane] = srow[wave][lane];
  if (ti != tj){
    #pragma unroll
    for (int nt=0;nt<4;nt++){
      float s = cs[nt].x + cs[nt].y;
      s += __shfl_xor(s,16); s += __shfl_xor(s,32);
      if (quad==0) scol[wave][nt*16 + cl] = s;
    }
    __threadfence_block();
    P[((long)tj*256 + ti)*64 + lane] = scol[wave][lane];
  }
}

// ---- fused final reduce + loss (256 blocks x 32 rows, 8 chunk-groups) ----
__global__ __launch_bounds__(256) void rloss_k(const float* __restrict__ P,
                                               const float* __restrict__ bdot,
                                               float* __restrict__ out){
  __shared__ float ps[8][32][2];
  const float E2 = 7.3890560989306495f;  // exp(2) = diag(refl)
  int t = threadIdx.x;
  int rloc = t & 31, grp = t >> 5;
  int i = blockIdx.x*32 + rloc;          // 0..8191
  int j = i + NROWS;
  const float* p1 = P + (long)(i>>6)*256*64 + (long)grp*32*64 + (i&63);
  const float* p2 = P + (long)(j>>6)*256*64 + (long)grp*32*64 + (j&63);
  float s1 = 0.f, s2 = 0.f;
  #pragma unroll 8
  for (int b=0;b<32;b++){ s1 += p1[b*64]; s2 += p2[b*64]; }
  ps[grp][rloc][0] = s1;
  ps[grp][rloc][1] = s2;
  __syncthreads();
  if (t < 64){
    float term = 0.f;
    if (t < 32){
      float a1 = 0.f, a2 = 0.f;
      #pragma unroll
      for (int g=0; g<8; g++){ a1 += ps[g][t][0]; a2 += ps[g][t][1]; }
      int ii = blockIdx.x*32 + t;
      float lb = 2.f * bdot[ii];
      term = 0.5f * ((logf(a1 - E2) - lb) + (logf(a2 - E2) - lb));
    }
    #pragma unroll
    for (int m=1; m<64; m<<=1) term += __shfl_xor(term, m);
    if (t==0) atomicAdd(out, term / (float)NROWS);
  }
}

extern "C" void kernel_launch(void* const* d_in, const int* in_sizes, int n_in,
                              void* d_out, int out_size, void* d_ws, size_t ws_size,
                              hipStream_t stream){
  const float* feat1 = (const float*)d_in[0];
  const float* feat2 = (const float*)d_in[1];
  const int*   ei1   = (const int*)d_in[2];
  const float* w1    = (const float*)d_in[3];
  const int*   ei2   = (const int*)d_in[4];
  const float* w2    = (const float*)d_in[5];
  const float* w_l1a = (const float*)d_in[6];
  const float* b_l1a = (const float*)d_in[7];
  const float* w_l1b = (const float*)d_in[8];
  const float* b_l1b = (const float*)d_in[9];
  const float* w_g1  = (const float*)d_in[10];
  const float* b_g1  = (const float*)d_in[11];
  const float* w_g2  = (const float*)d_in[12];
  const float* b_g2  = (const float*)d_in[13];
  const float* w_fc1 = (const float*)d_in[14];
  const float* b_fc1 = (const float*)d_in[15];
  const float* w_fc2 = (const float*)d_in[16];
  const float* b_fc2 = (const float*)d_in[17];

  float* P = (float*)d_ws;          // 16.8MB partials at ws base
  char* base = (char*)d_ws;
  size_t off = (size_t)17<<20;      // live buffers beyond P
  auto alloc = [&](size_t bytes)->void*{
    void* r = base + off;
    off = (off + bytes + 255) & ~(size_t)255;
    return r;
  };
  short* xb   = (short*)alloc((size_t)MROWS*32*2);
  short* s2   = (short*)alloc((size_t)MROWS*128*2);
  short* wl1a_t = (short*)alloc(512*64*2);
  short* wl1b_t = (short*)alloc(64*32*2);
  short* wg1_t  = (short*)alloc(32*256*2);
  short* wg2_t  = (short*)alloc(256*128*2);
  short* wfc1_t = (short*)alloc(128*64*2);
  short* wfc2_t = (short*)alloc(64*128*2);
  unsigned short* Zf = (unsigned short*)alloc((size_t)MROWS*128);   // fragment-order fp8
  int*   deg1 = (int*)alloc(NROWS*4);                               // zeroed pair
  int*   deg2 = (int*)alloc(NROWS*4);
  int* rs1  = (int*)alloc((NROWS+1)*4);
  int* cur1 = (int*)alloc(NROWS*4);
  int* rs2  = (int*)alloc((NROWS+1)*4);
  int* cur2 = (int*)alloc(NROWS*4);
  int2*  eg1 = (int2*)alloc((size_t)NEDGE*8);   // packed {col, weight-bits}
  int2*  eg2 = (int2*)alloc((size_t)NEDGE*8);
  float* bdot  = (float*)alloc(NROWS*4);

  hipMemsetAsync(deg1, 0, (size_t)2*NROWS*4, stream);
  hipMemsetAsync(d_out, 0, sizeof(float), stream);

  WtArgs wa;
  wa.src[0]=w_l1a; wa.dst[0]=wl1a_t; wa.K[0]=512; wa.N[0]=64;
  wa.src[1]=w_l1b; wa.dst[1]=wl1b_t; wa.K[1]=64;  wa.N[1]=32;
  wa.src[2]=w_g1;  wa.dst[2]=wg1_t;  wa.K[2]=32;  wa.N[2]=256;
  wa.src[3]=w_g2;  wa.dst[3]=wg2_t;  wa.K[3]=256; wa.N[3]=128;
  wa.src[4]=w_fc1; wa.dst[4]=wfc1_t; wa.K[4]=128; wa.N[4]=64;
  wa.src[5]=w_fc2; wa.dst[5]=wfc2_t; wa.K[5]=64;  wa.N[5]=128;
  wa.off[0]=0;
  for (int i=0;i<6;i++) wa.off[i+1] = wa.off[i] + wa.K[i]*wa.N[i];
  wa.nwt = (wa.off[6]+255)/256;

  setup_k<<<wa.nwt + 2*(NEDGE/256),256,0,stream>>>(wa, ei1, ei2, deg1, deg2);
  scan2_k<<<2,256,0,stream>>>(deg1, rs1, cur1, deg2, rs2, cur2);
  fm_k<<<NFILLB + MROWS/32,256,0,stream>>>(feat1, feat2, wl1a_t, b_l1a,
      wl1b_t, b_l1b, xb,
      ei1, w1, cur1, eg1,
      ei2, w2, cur2, eg2);
  gg_k<<<MROWS/64,256,0,stream>>>(xb, rs1,eg1, rs2,eg2,
                                  wg1_t, b_g1, wg2_t, s2);
  pn_k<<<NROWS/32,256,0,stream>>>(s2, rs1,eg1, rs2,eg2, b_g2,
                                  wfc1_t, b_fc1, wfc2_t, b_fc2, Zf, bdot);
  gram3_k<<<8224,256,0,stream>>>((const unsigned char*)Zf, P);   // 32896 UT tiles
  rloss_k<<<NROWS/32,256,0,stream>>>(P, bdot, (float*)d_out);
}

// Round 10
// 249.764 us; speedup vs baseline: 1.0147x; 1.0147x over previous
//
#include <hip/hip_runtime.h>
#include <hip/hip_bf16.h>
#include <math.h>

// GRACE-style graph contrastive loss, MI355X (gfx950).
// R24: un-fuse fill+mlp. R23's A/B bundle showed: int2 packing cut WRITE
// 40->33MB (keep), but EPT=8 cut occupancy/TLP and regressed (revert to 1
// edge/thread). Root defect hypothesis: the R19 fusion itself — mlp's 37.9KB
// static LDS caps ALL blocks (incl. LDS-free fill blocks) at 4/CU, and the
// fused kernel idles at <3% VALU / 15% HBM / 25% occ. Split: fill2_k (no LDS,
// 2048 one-shot blocks, packed int2 store, full occupancy) + mlp12_k (R18
// form). gg/pn packed readers kept; gram3 (R18), fused gather->pn, parallel
// rloss unchanged. Baseline to beat: 247.1us (R22).

#define NROWS 8192
#define MROWS 16384
#define NEDGE 262144

typedef __attribute__((ext_vector_type(8))) short bf16x8;
typedef __attribute__((ext_vector_type(4))) float f32x4;
typedef __attribute__((ext_vector_type(2))) float f32x2;
typedef __attribute__((ext_vector_type(8))) int i32x8;
typedef long long i64;

__device__ __forceinline__ short f2bf(float f){
  union { float f; unsigned u; } cv; cv.f = f;
  unsigned u = cv.u;
  unsigned r = (u + 0x7fffu + ((u >> 16) & 1u)) >> 16;  // RNE; inputs finite
  return (short)r;
}
__device__ __forceinline__ f32x4 mfma16(bf16x8 a, bf16x8 b, f32x4 c){
  return __builtin_amdgcn_mfma_f32_16x16x32_bf16(a, b, c, 0, 0, 0);
}
__device__ __forceinline__ float fexp2(float x){
#if __has_builtin(__builtin_amdgcn_exp2f)
  return __builtin_amdgcn_exp2f(x);
#else
  return exp2f(x);
#endif
}

// DPP row_shl add: lane i += lane(i+N) within each 16-lane row (0 beyond row
// edge via bound_ctrl). Chain {1,2,4,8}: lane 0 of each row accumulates the
// balanced tree ((v0+v1)+(v2+v3))+... == xor butterfly's lane-0 result.
template<int CTRL>
__device__ __forceinline__ float dpp_add(float v){
  int s = __builtin_amdgcn_update_dpp(0, __builtin_bit_cast(int, v),
                                      CTRL, 0xf, 0xf, true);
  return v + __builtin_bit_cast(float, s);
}
__device__ __forceinline__ float red16(float v){
  v = dpp_add<0x101>(v);   // row_shl:1
  v = dpp_add<0x102>(v);   // row_shl:2
  v = dpp_add<0x104>(v);   // row_shl:4
  v = dpp_add<0x108>(v);   // row_shl:8
  return v;
}

// ---- fp8 e4m3fn pack (RNE) ----
__device__ unsigned char f2e4m3_sw(float f){
  float a = fabsf(f);
  unsigned s = (__float_as_uint(f)>>24)&0x80u;
  if (!(a>0.f)) return (unsigned char)s;
  if (a>448.f) a=448.f;
  int e; frexpf(a,&e);
  int eff=e-1;
  unsigned code;
  if (eff<-6){
    float q=rintf(a*512.f);
    code=(unsigned)q; if(code>7)code=7;
  } else {
    float q=rintf(a*exp2f((float)(3-eff)));
    unsigned mant=(unsigned)q;
    if(mant>=16){mant=8;eff++;}
    if(eff>8) return (unsigned char)(s|0x7e);
    code=((unsigned)(eff+7)<<3)|(mant-8);
  }
  return (unsigned char)(s|code);
}
__device__ __forceinline__ unsigned short pack2fp8(float a, float b){
#if __has_builtin(__builtin_amdgcn_cvt_pk_fp8_f32)
  int v = __builtin_amdgcn_cvt_pk_fp8_f32(a, b, 0, false);
  return (unsigned short)(v & 0xffff);
#else
  return (unsigned short)((unsigned)f2e4m3_sw(a) | ((unsigned)f2e4m3_sw(b)<<8));
#endif
}

// ---- setup: weight transpose+bf16 (6 weights) | degree histogram ----
struct WtArgs {
  const float* src[6];
  short* dst[6];
  int K[6], N[6];
  int off[7];
  int nwt;
};
__global__ void setup_k(WtArgs a, const int* __restrict__ ei1, const int* __restrict__ ei2,
                        int* __restrict__ deg1, int* __restrict__ deg2){
  int b = blockIdx.x;
  if (b < a.nwt){
    int i = b*256 + threadIdx.x;
    if (i >= a.off[6]) return;
    int s = 0;
    #pragma unroll
    for (int j=1;j<6;j++) if (i >= a.off[j]) s=j;
    int l = i - a.off[s];
    int K=a.K[s], N=a.N[s];
    int k=l/N, n=l-k*N;
    a.dst[s][(long)n*K+k] = f2bf(a.src[s][l]);
  } else {
    int hb = b - a.nwt;
    const int* ei = (hb < NEDGE/256) ? ei1 : ei2;
    int* deg = (hb < NEDGE/256) ? deg1 : deg2;
    int e = (hb % (NEDGE/256))*256 + threadIdx.x;
    atomicAdd(&deg[ei[e]], 1);
  }
}

// ---- CSR build: scan ----
__global__ void scan2_k(const int* __restrict__ deg1, int* __restrict__ rs1, int* __restrict__ cur1,
                        const int* __restrict__ deg2, int* __restrict__ rs2, int* __restrict__ cur2){
  const int* deg = blockIdx.x ? deg2 : deg1;
  int* rowstart = blockIdx.x ? rs2 : rs1;
  int* cursor = blockIdx.x ? cur2 : cur1;
  __shared__ int csum[256];
  int t = threadIdx.x;
  int loc[32];
  int s = 0;
  for (int j=0;j<32;j++){ int d = deg[t*32+j]; loc[j] = s; s += d; }
  // inclusive Hillis-Steele scan of per-thread totals
  int v = s;
  csum[t] = v;
  __syncthreads();
  for (int st=1; st<256; st<<=1){
    int o = (t >= st) ? csum[t-st] : 0;
    __syncthreads();
    v += o;
    csum[t] = v;
    __syncthreads();
  }
  int base = v - s;   // exclusive prefix for this thread's 32 rows
  for (int j=0;j<32;j++){ int w = base + loc[j]; rowstart[t*32+j]=w; cursor[t*32+j]=w; }
  if (t==255) rowstart[NROWS] = v;
}

// ---- fill2_k: standalone CSR fill — no LDS, full occupancy, 1 edge/thread,
// packed int2 {col, weight-bits} payload (one 8B scattered store/edge). ----
__global__ void fill2_k(const int* __restrict__ ei1, const float* __restrict__ w1,
                        int* __restrict__ cur1, int2* __restrict__ eg1,
                        const int* __restrict__ ei2, const float* __restrict__ w2,
                        int* __restrict__ cur2, int2* __restrict__ eg2){
  int b = blockIdx.x;
  bool g2 = (b >= NEDGE/256);
  const int* ei = g2 ? ei2 : ei1;
  const float* w = g2 ? w2 : w1;
  int* cursor = g2 ? cur2 : cur1;
  int2* eg = g2 ? eg2 : eg1;
  int e = (b % (NEDGE/256))*256 + threadIdx.x;
  int r = ei[e];
  int c = ei[NEDGE + e];
  float wv = w[e];
  int p = atomicAdd(&cursor[r], 1);
  eg[p] = make_int2(c, __float_as_int(wv));
}

// ---- mlp12_k: xb[M,32] = (relu(feat@Wa+ba))@Wb+bb. 512 blocks x 32 rows. ----
__global__ __launch_bounds__(256) void mlp12_k(const float* __restrict__ F0, const float* __restrict__ F1,
                                               const short* __restrict__ Wa, const float* __restrict__ ba,
                                               const short* __restrict__ Wb, const float* __restrict__ bb,
                                               short* __restrict__ xb){
  __shared__ short As[32*520];   // 32x512 bf16, +8 pad
  __shared__ short a1s[32*72];   // 32x64 bf16, +8 pad
  const int tid = threadIdx.x;
  const int m0 = blockIdx.x*32;
  const float* F = (m0 < NROWS) ? (F0 + (long)m0*512) : (F1 + (long)(m0-NROWS)*512);
  {
    float4 st[16];
    #pragma unroll
    for (int i=0;i<16;i++) st[i] = *(const float4*)(F + (long)(i*256+tid)*4);
    #pragma unroll
    for (int i=0;i<16;i++){
      int idx = i*256+tid, row = idx>>7, c4 = idx&127;
      unsigned lo = (unsigned)(unsigned short)f2bf(st[i].x) | ((unsigned)(unsigned short)f2bf(st[i].y)<<16);
      unsigned hi = (unsigned)(unsigned short)f2bf(st[i].z) | ((unsigned)(unsigned short)f2bf(st[i].w)<<16);
      uint2 o = {lo, hi};
      *(uint2*)&As[row*520 + c4*4] = o;
    }
  }
  __syncthreads();
  const int wave = tid>>6, lane = tid&63, quad = lane>>4, cl = lane&15;
  f32x4 zero = {0.f,0.f,0.f,0.f};
  {
    // stage1: 32 rows (MT=2) x 16 cols per wave, K=512
    const int wno = wave*16;
    f32x4 acc[2] = {zero, zero};
    #pragma unroll
    for (int kc=0;kc<16;kc++){
      const int ko = kc*32 + quad*8;
      bf16x8 a0 = *(const bf16x8*)&As[(cl)*520 + ko];
      bf16x8 a1 = *(const bf16x8*)&As[(16+cl)*520 + ko];
      bf16x8 b = *(const bf16x8*)(Wa + (long)(wno + cl)*512 + ko);
      acc[0] = mfma16(a0, b, acc[0]);
      acc[1] = mfma16(a1, b, acc[1]);
    }
    int col = wno + cl;
    float bv = ba[col];
    #pragma unroll
    for (int mt=0;mt<2;mt++)
      #pragma unroll
      for (int r=0;r<4;r++)
        a1s[(mt*16 + quad*4 + r)*72 + col] = f2bf(fmaxf(acc[mt][r] + bv, 0.f));
  }
  __syncthreads();
  if (wave < 2){
    // stage2: wave w -> rows w*16..+15, full 32 cols (NT=2), K=64
    f32x4 acc2[2] = {zero, zero};
    #pragma unroll
    for (int kc=0;kc<2;kc++){
      const int ko = kc*32 + quad*8;
      bf16x8 a = *(const bf16x8*)&a1s[(wave*16+cl)*72 + ko];
      #pragma unroll
      for (int nt=0;nt<2;nt++){
        bf16x8 b = *(const bf16x8*)(Wb + (long)(nt*16 + cl)*64 + ko);
        acc2[nt] = mfma16(a, b, acc2[nt]);
      }
    }
    #pragma unroll
    for (int nt=0;nt<2;nt++){
      int col = nt*16 + cl;
      float bv = bb[col];
      #pragma unroll
      for (int r=0;r<4;r++)
        xb[(long)(m0 + wave*16 + quad*4 + r)*32 + col] = f2bf(acc2[nt][r] + bv);
    }
  }
}

// ---- gather helpers (packed int2 edges: x=col, y=weight bits) ----
__device__ __forceinline__ void acc8(float* acc, int4 v, float f){
  const unsigned* u = (const unsigned*)&v;
  #pragma unroll
  for (int i=0;i<4;i++){
    union{unsigned x; float y;} lo, hi;
    lo.x = u[i] << 16;
    hi.x = u[i] & 0xffff0000u;
    acc[2*i]   = fmaf(f, lo.y, acc[2*i]);
    acc[2*i+1] = fmaf(f, hi.y, acc[2*i+1]);
  }
}
template<int C>
__device__ __forceinline__ void gather_row(float* acc, const short* sb,
                                           const int2* eg, int s, int e){
  int k = s;
  for (; k+16 <= e; k+=16){
    int2 cw[16]; int4 v[16];
    #pragma unroll
    for (int u=0;u<16;u++) cw[u] = eg[k+u];
    #pragma unroll
    for (int u=0;u<16;u++) v[u] = *(const int4*)(sb + (long)cw[u].x*C);
    #pragma unroll
    for (int u=0;u<16;u++) acc8(acc, v[u], __int_as_float(cw[u].y));
  }
  for (; k+4 <= e; k+=4){
    int2 c0=eg[k], c1=eg[k+1], c2=eg[k+2], c3=eg[k+3];
    int4 v0 = *(const int4*)(sb + (long)c0.x*C);
    int4 v1 = *(const int4*)(sb + (long)c1.x*C);
    int4 v2 = *(const int4*)(sb + (long)c2.x*C);
    int4 v3 = *(const int4*)(sb + (long)c3.x*C);
    acc8(acc,v0,__int_as_float(c0.y)); acc8(acc,v1,__int_as_float(c1.y));
    acc8(acc,v2,__int_as_float(c2.y)); acc8(acc,v3,__int_as_float(c3.y));
  }
  for (; k < e; k++){
    int2 c0 = eg[k];
    int4 v0 = *(const int4*)(sb + (long)c0.x*C);
    acc8(acc,v0,__int_as_float(c0.y));
  }
}

// ---- gg_k: gather32 (adj@xb -> LDS) + g34 (relu(ax@Wg1+bg1)@Wg2 -> s2) ----
__global__ __launch_bounds__(256) void gg_k(const short* __restrict__ xb,
    const int* __restrict__ rs1, const int2* __restrict__ eg1,
    const int* __restrict__ rs2, const int2* __restrict__ eg2,
    const short* __restrict__ Wg1, const float* __restrict__ bg1,
    const short* __restrict__ Wg2, short* __restrict__ s2){
  __shared__ short axs[64*40];    // gathered ax tile (pad 8)
  __shared__ short hbs[64*264];   // relu(ax@Wg1+b) tile (pad 8)
  const int tid = threadIdx.x;
  const int m0 = blockIdx.x*64;
  {
    const int g = tid & 3, sub = tid >> 2;
    const int row = m0 + sub;
    const int* rs; const int2* eg; int soff, lr;
    if (row < NROWS){ rs=rs1; eg=eg1; soff=0; lr=row; }
    else            { rs=rs2; eg=eg2; soff=NROWS; lr=row-NROWS; }
    const short* sb = xb + (long)soff*32 + g*8;
    float acc[8];
    #pragma unroll
    for (int j=0;j<8;j++) acc[j] = 0.f;
    gather_row<32>(acc, sb, eg, rs[lr], rs[lr+1]);
    int4 ov;
    unsigned* ou = (unsigned*)&ov;
    #pragma unroll
    for (int i=0;i<4;i++)
      ou[i] = (unsigned)(unsigned short)f2bf(acc[2*i]) | ((unsigned)(unsigned short)f2bf(acc[2*i+1])<<16);
    *(int4*)&axs[sub*40 + g*8] = ov;
  }
  __syncthreads();
  const int wave = tid>>6, lane = tid&63, quad = lane>>4, cl = lane&15;
  f32x4 zero = {0.f,0.f,0.f,0.f};
  {
    const int wno = wave*64;
    f32x4 acc[4][4];
    #pragma unroll
    for (int i=0;i<4;i++)
      #pragma unroll
      for (int j=0;j<4;j++) acc[i][j]=zero;
    const int ko = quad*8;
    bf16x8 a[4], b[4];
    #pragma unroll
    for (int mt=0;mt<4;mt++)
      a[mt] = *(const bf16x8*)&axs[(mt*16+cl)*40 + ko];
    #pragma unroll
    for (int nt=0;nt<4;nt++)
      b[nt] = *(const bf16x8*)(Wg1 + (long)(wno + nt*16 + cl)*32 + ko);
    #pragma unroll
    for (int mt=0;mt<4;mt++)
      #pragma unroll
      for (int nt=0;nt<4;nt++)
        acc[mt][nt] = mfma16(a[mt], b[nt], acc[mt][nt]);
    #pragma unroll
    for (int nt=0;nt<4;nt++){
      int col = wno + nt*16 + cl;
      float bv = bg1[col];
      #pragma unroll
      for (int mt=0;mt<4;mt++)
        #pragma unroll
        for (int r=0;r<4;r++)
          hbs[(mt*16 + quad*4 + r)*264 + col] = f2bf(fmaxf(acc[mt][nt][r] + bv, 0.f));
    }
  }
  __syncthreads();
  {
    const int wno = wave*32;
    f32x4 acc[4][2];
    #pragma unroll
    for (int i=0;i<4;i++){ acc[i][0]=zero; acc[i][1]=zero; }
    #pragma unroll
    for (int kc=0;kc<8;kc++){
      const int ko = kc*32 + quad*8;
      bf16x8 a[4], b[2];
      #pragma unroll
      for (int mt=0;mt<4;mt++)
        a[mt] = *(const bf16x8*)&hbs[(mt*16+cl)*264 + ko];
      #pragma unroll
      for (int nt=0;nt<2;nt++)
        b[nt] = *(const bf16x8*)(Wg2 + (long)(wno + nt*16 + cl)*256 + ko);
      #pragma unroll
      for (int mt=0;mt<4;mt++)
        #pragma unroll
        for (int nt=0;nt<2;nt++)
          acc[mt][nt] = mfma16(a[mt], b[nt], acc[mt][nt]);
    }
    #pragma unroll
    for (int mt=0;mt<4;mt++)
      #pragma unroll
      for (int nt=0;nt<2;nt++){
        int col = wno + nt*16 + cl;
        #pragma unroll
        for (int r=0;r<4;r++)
          s2[(long)(m0 + mt*16 + quad*4 + r)*128 + col] = f2bf(acc[mt][nt][r]);
      }
  }
}

// ---- pn_k: layer-2 aggregation (gathered in-block) + proj1(elu) +
// proj2 + normalize + fp8-quantize, PAIR-ROW blocks. ----
__global__ __launch_bounds__(256) void pn_k(const short* __restrict__ s2,
    const int* __restrict__ rs1, const int2* __restrict__ eg1,
    const int* __restrict__ rs2, const int2* __restrict__ eg2,
    const float* __restrict__ bg2,
    const short* __restrict__ Wf1, const float* __restrict__ bf1,
    const short* __restrict__ Wf2, const float* __restrict__ bf2,
    unsigned short* __restrict__ Zf, float* __restrict__ bdot){
  __shared__ short hs[64*136];
  __shared__ short t2s[64*72];
  __shared__ float zs[64*132];
  __shared__ float sp[4][64];
  __shared__ float dp[4][32];
  __shared__ float rnS[64];
  const float SQKE = 1.6986436f;   // sqrt(2*log2(e))
  const int tid = threadIdx.x;
  const int wave = tid>>6, lane = tid&63, quad = lane>>4, cl = lane&15;
  const int m0h = blockIdx.x*32;
  {
    // gather 64 rows into hs: rows 0..31 = graph1, rows 32..63 = graph2.
    const int g = tid & 15, sub = tid >> 4;
    #pragma unroll 1
    for (int pass=0; pass<4; pass++){
      int hrow = pass*16 + sub;
      int lr = m0h + (hrow & 31);
      const int* rs; const int2* eg; long soff;
      if (hrow < 32){ rs=rs1; eg=eg1; soff=0; }
      else          { rs=rs2; eg=eg2; soff=NROWS; }
      const short* sb = s2 + soff*128 + g*8;
      float acc[8];
      #pragma unroll
      for (int j=0;j<8;j++) acc[j] = bg2[g*8+j];
      gather_row<128>(acc, sb, eg, rs[lr], rs[lr+1]);
      int4 ov;
      unsigned* ou = (unsigned*)&ov;
      #pragma unroll
      for (int i=0;i<4;i++)
        ou[i] = (unsigned)(unsigned short)f2bf(acc[2*i]) | ((unsigned)(unsigned short)f2bf(acc[2*i+1])<<16);
      *(int4*)&hs[hrow*136 + g*8] = ov;
    }
  }
  __syncthreads();
  f32x4 zero = {0.f,0.f,0.f,0.f};
  {
    // proj1: NN=64, K=128, elu -> t2s
    const int wno = wave*16;
    f32x4 acc[4];
    #pragma unroll
    for (int i=0;i<4;i++) acc[i]=zero;
    #pragma unroll
    for (int kc=0;kc<4;kc++){
      const int ko = kc*32 + quad*8;
      bf16x8 a[4], b;
      #pragma unroll
      for (int mt=0;mt<4;mt++)
        a[mt] = *(const bf16x8*)&hs[(mt*16+cl)*136 + ko];
      b = *(const bf16x8*)(Wf1 + (long)(wno + cl)*128 + ko);
      #pragma unroll
      for (int mt=0;mt<4;mt++) acc[mt] = mfma16(a[mt], b, acc[mt]);
    }
    int col = wno + cl;
    float bv = bf1[col];
    #pragma unroll
    for (int mt=0;mt<4;mt++)
      #pragma unroll
      for (int r=0;r<4;r++){
        float v = acc[mt][r] + bv;
        v = (v > 0.f) ? v : expm1f(v);
        t2s[(mt*16 + quad*4 + r)*72 + col] = f2bf(v);
      }
  }
  __syncthreads();
  {
    // proj2: NN=128, K=64 -> zs (fp32)
    const int wno = wave*32;
    f32x4 acc[4][2];
    #pragma unroll
    for (int i=0;i<4;i++){ acc[i][0]=zero; acc[i][1]=zero; }
    #pragma unroll
    for (int kc=0;kc<2;kc++){
      const int ko = kc*32 + quad*8;
      bf16x8 a[4], b[2];
      #pragma unroll
      for (int mt=0;mt<4;mt++)
        a[mt] = *(const bf16x8*)&t2s[(mt*16+cl)*72 + ko];
      #pragma unroll
      for (int nt=0;nt<2;nt++)
        b[nt] = *(const bf16x8*)(Wf2 + (long)(wno + nt*16 + cl)*64 + ko);
      #pragma unroll
      for (int mt=0;mt<4;mt++)
        #pragma unroll
        for (int nt=0;nt<2;nt++)
          acc[mt][nt] = mfma16(a[mt], b[nt], acc[mt][nt]);
    }
    #pragma unroll
    for (int mt=0;mt<4;mt++)
      #pragma unroll
      for (int nt=0;nt<2;nt++){
        int col = wno + nt*16 + cl;
        float bv = bf2[col];
        #pragma unroll
        for (int r=0;r<4;r++)
          zs[(mt*16 + quad*4 + r)*132 + col] = acc[mt][nt][r] + bv;
      }
  }
  __syncthreads();
  {
    int row = tid & 63, qtr = tid >> 6;
    const float* zr = &zs[row*132 + qtr*32];
    float s = 0.f;
    #pragma unroll 8
    for (int c=0;c<32;c++) s += zr[c]*zr[c];
    sp[qtr][row] = s;
    if (row < 32){
      const float* zb_ = &zs[(row+32)*132 + qtr*32];
      float d = 0.f;
      #pragma unroll 8
      for (int c=0;c<32;c++) d += zr[c]*zb_[c];
      dp[qtr][row] = d;
    }
  }
  __syncthreads();
  if (tid < 64){
    float ssq = sp[0][tid]+sp[1][tid]+sp[2][tid]+sp[3][tid];
    rnS[tid] = 1.f / fmaxf(sqrtf(ssq), 1e-12f);
  }
  __syncthreads();
  if (tid < 32){
    float dot = dp[0][tid]+dp[1][tid]+dp[2][tid]+dp[3][tid];
    bdot[m0h + tid] = dot * rnS[tid] * rnS[tid+32];
  }
  {
    // fp8*sqrt(KE) quantize into K=128 f8f6f4 fragment-order Zf.
    int lr = tid >> 2;
    int grow = (lr < 32) ? (m0h + lr) : (NROWS + m0h + lr - 32);
    float s = rnS[lr] * SQKE;
    int p0 = (tid & 3)*16;
    long gbase = (long)(grow>>4)*1024 + (long)(grow&15)*16 + (long)(p0>>4)*256;
    #pragma unroll
    for (int pp=0;pp<16;pp++){
      int p = p0 + pp;
      Zf[gbase + pp] = pack2fp8(zs[lr*132 + 2*p]*s, zs[lr*132 + 2*p + 1]*s);
    }
  }
}

// ---- symmetric exp-Gram partials (R18 form: single tile/wave, MX K=128
// MFMA scale=1.0, strip pipeline, DPP row_shl reduce; VGPR 60, no spill).
__global__ __launch_bounds__(256,4) void gram3_k(const unsigned char* __restrict__ Zf,
                                                 float* __restrict__ P){
  __shared__ float srow[4][64];
  __shared__ float scol[4][64];
  const int wave = threadIdx.x>>6, lane = threadIdx.x&63;
  const int t = blockIdx.x*4 + wave;           // UT tile index, T=256
  int ti = (int)((513.0f - sqrtf(513.0f*513.0f - 8.0f*(float)t))*0.5f);
  while ((ti+1)*256 - ((ti+1)*ti)/2 <= t) ti++;
  while (ti*256 - (ti*(ti-1))/2 > t) ti--;
  const int tj = ti + (t - (ti*256 - (ti*(ti-1))/2));
  // 64-row tile = 4 groups x 2048B; lane reads 32 contiguous K-bytes
  const unsigned char* za = Zf + (long)ti*8192 + lane*32;
  const unsigned char* zb = Zf + (long)tj*8192 + lane*32;
  const int quad = lane>>4, cl = lane&15;

  f32x4 zero = {0.f,0.f,0.f,0.f};
  f32x2 z2 = {0.f,0.f};
  f32x2 cs[4] = {z2,z2,z2,z2};

  // all B fragments resident: Bf[nt] (v8i32 each)
  i32x8 Bf[4];
  #pragma unroll
  for (int nt=0;nt<4;nt++)
    Bf[nt] = *(const i32x8*)(zb + nt*2048);

  // A double-buffer: strip mt lives in Ab[mt&1]
  i32x8 Ab[2];
  Ab[0] = *(const i32x8*)(za);
  Ab[1] = *(const i32x8*)(za + 2048);

  // exp + row-sum reduce of one 16-row strip; DPP row_shl tree (lane cl==0
  // result bit-identical to the xor butterfly's).
  auto exprow = [&](const f32x4* ar, int mt){
    f32x2 r01 = z2, r23 = z2;
    #pragma unroll
    for (int nt=0;nt<4;nt++){
      f32x4 v = ar[nt];
      float e0 = fexp2(v[0]), e1 = fexp2(v[1]);
      float e2 = fexp2(v[2]), e3 = fexp2(v[3]);
      f32x2 p01 = {e0,e1}, p23 = {e2,e3};
      r01 += p01; r23 += p23;
      cs[nt] += p01; cs[nt] += p23;
    }
    float s0 = red16(r01.x);
    float s1 = red16(r01.y);
    float s2 = red16(r23.x);
    float s3 = red16(r23.y);
    if (cl==0){
      f32x4 rv = {s0, s1, s2, s3};
      *(f32x4*)&srow[wave][mt*16 + quad*4] = rv;
    }
  };

  const int SC1 = 0x7F;   // e8m0 scale = 2^0
  f32x4 acc2[2][4];
  // strip 0: one K=128 MFMA per nt
  #pragma unroll
  for (int nt=0;nt<4;nt++)
    acc2[0][nt] = __builtin_amdgcn_mfma_scale_f32_16x16x128_f8f6f4(
        Ab[0], Bf[nt], zero, 0, 0, 0, SC1, 0, SC1);
  // strips 1..3: prefetch A, issue MFMAs, exp previous strip underneath
  #pragma unroll
  for (int mt=1; mt<4; mt++){
    const int cur = mt&1, prv = cur^1;
    if (mt<3)
      Ab[prv] = *(const i32x8*)(za + (mt+1)*2048);
    #pragma unroll
    for (int nt=0;nt<4;nt++)
      acc2[cur][nt] = __builtin_amdgcn_mfma_scale_f32_16x16x128_f8f6f4(
          Ab[cur], Bf[nt], zero, 0, 0, 0, SC1, 0, SC1);
    exprow(&acc2[prv][0], mt-1);
  }
  exprow(&acc2[1][0], 3);

  __threadfence_block();
  P[((long)ti*256 + tj)*64 + lane] = srow[wave][lane];
  if (ti != tj){
    #pragma unroll
    for (int nt=0;nt<4;nt++){
      float s = cs[nt].x + cs[nt].y;
      s += __shfl_xor(s,16); s += __shfl_xor(s,32);
      if (quad==0) scol[wave][nt*16 + cl] = s;
    }
    __threadfence_block();
    P[((long)tj*256 + ti)*64 + lane] = scol[wave][lane];
  }
}

// ---- fused final reduce + loss (256 blocks x 32 rows, 8 chunk-groups) ----
__global__ __launch_bounds__(256) void rloss_k(const float* __restrict__ P,
                                               const float* __restrict__ bdot,
                                               float* __restrict__ out){
  __shared__ float ps[8][32][2];
  const float E2 = 7.3890560989306495f;  // exp(2) = diag(refl)
  int t = threadIdx.x;
  int rloc = t & 31, grp = t >> 5;
  int i = blockIdx.x*32 + rloc;          // 0..8191
  int j = i + NROWS;
  const float* p1 = P + (long)(i>>6)*256*64 + (long)grp*32*64 + (i&63);
  const float* p2 = P + (long)(j>>6)*256*64 + (long)grp*32*64 + (j&63);
  float s1 = 0.f, s2 = 0.f;
  #pragma unroll 8
  for (int b=0;b<32;b++){ s1 += p1[b*64]; s2 += p2[b*64]; }
  ps[grp][rloc][0] = s1;
  ps[grp][rloc][1] = s2;
  __syncthreads();
  if (t < 64){
    float term = 0.f;
    if (t < 32){
      float a1 = 0.f, a2 = 0.f;
      #pragma unroll
      for (int g=0; g<8; g++){ a1 += ps[g][t][0]; a2 += ps[g][t][1]; }
      int ii = blockIdx.x*32 + t;
      float lb = 2.f * bdot[ii];
      term = 0.5f * ((logf(a1 - E2) - lb) + (logf(a2 - E2) - lb));
    }
    #pragma unroll
    for (int m=1; m<64; m<<=1) term += __shfl_xor(term, m);
    if (t==0) atomicAdd(out, term / (float)NROWS);
  }
}

extern "C" void kernel_launch(void* const* d_in, const int* in_sizes, int n_in,
                              void* d_out, int out_size, void* d_ws, size_t ws_size,
                              hipStream_t stream){
  const float* feat1 = (const float*)d_in[0];
  const float* feat2 = (const float*)d_in[1];
  const int*   ei1   = (const int*)d_in[2];
  const float* w1    = (const float*)d_in[3];
  const int*   ei2   = (const int*)d_in[4];
  const float* w2    = (const float*)d_in[5];
  const float* w_l1a = (const float*)d_in[6];
  const float* b_l1a = (const float*)d_in[7];
  const float* w_l1b = (const float*)d_in[8];
  const float* b_l1b = (const float*)d_in[9];
  const float* w_g1  = (const float*)d_in[10];
  const float* b_g1  = (const float*)d_in[11];
  const float* w_g2  = (const float*)d_in[12];
  const float* b_g2  = (const float*)d_in[13];
  const float* w_fc1 = (const float*)d_in[14];
  const float* b_fc1 = (const float*)d_in[15];
  const float* w_fc2 = (const float*)d_in[16];
  const float* b_fc2 = (const float*)d_in[17];

  float* P = (float*)d_ws;          // 16.8MB partials at ws base
  char* base = (char*)d_ws;
  size_t off = (size_t)17<<20;      // live buffers beyond P
  auto alloc = [&](size_t bytes)->void*{
    void* r = base + off;
    off = (off + bytes + 255) & ~(size_t)255;
    return r;
  };
  short* xb   = (short*)alloc((size_t)MROWS*32*2);
  short* s2   = (short*)alloc((size_t)MROWS*128*2);
  short* wl1a_t = (short*)alloc(512*64*2);
  short* wl1b_t = (short*)alloc(64*32*2);
  short* wg1_t  = (short*)alloc(32*256*2);
  short* wg2_t  = (short*)alloc(256*128*2);
  short* wfc1_t = (short*)alloc(128*64*2);
  short* wfc2_t = (short*)alloc(64*128*2);
  unsigned short* Zf = (unsigned short*)alloc((size_t)MROWS*128);   // fragment-order fp8
  int*   deg1 = (int*)alloc(NROWS*4);                               // zeroed pair
  int*   deg2 = (int*)alloc(NROWS*4);
  int* rs1  = (int*)alloc((NROWS+1)*4);
  int* cur1 = (int*)alloc(NROWS*4);
  int* rs2  = (int*)alloc((NROWS+1)*4);
  int* cur2 = (int*)alloc(NROWS*4);
  int2*  eg1 = (int2*)alloc((size_t)NEDGE*8);   // packed {col, weight-bits}
  int2*  eg2 = (int2*)alloc((size_t)NEDGE*8);
  float* bdot  = (float*)alloc(NROWS*4);

  hipMemsetAsync(deg1, 0, (size_t)2*NROWS*4, stream);
  hipMemsetAsync(d_out, 0, sizeof(float), stream);

  WtArgs wa;
  wa.src[0]=w_l1a; wa.dst[0]=wl1a_t; wa.K[0]=512; wa.N[0]=64;
  wa.src[1]=w_l1b; wa.dst[1]=wl1b_t; wa.K[1]=64;  wa.N[1]=32;
  wa.src[2]=w_g1;  wa.dst[2]=wg1_t;  wa.K[2]=32;  wa.N[2]=256;
  wa.src[3]=w_g2;  wa.dst[3]=wg2_t;  wa.K[3]=256; wa.N[3]=128;
  wa.src[4]=w_fc1; wa.dst[4]=wfc1_t; wa.K[4]=128; wa.N[4]=64;
  wa.src[5]=w_fc2; wa.dst[5]=wfc2_t; wa.K[5]=64;  wa.N[5]=128;
  wa.off[0]=0;
  for (int i=0;i<6;i++) wa.off[i+1] = wa.off[i] + wa.K[i]*wa.N[i];
  wa.nwt = (wa.off[6]+255)/256;

  setup_k<<<wa.nwt + 2*(NEDGE/256),256,0,stream>>>(wa, ei1, ei2, deg1, deg2);
  scan2_k<<<2,256,0,stream>>>(deg1, rs1, cur1, deg2, rs2, cur2);
  fill2_k<<<2*(NEDGE/256),256,0,stream>>>(ei1, w1, cur1, eg1,
                                          ei2, w2, cur2, eg2);
  mlp12_k<<<MROWS/32,256,0,stream>>>(feat1, feat2, wl1a_t, b_l1a, wl1b_t, b_l1b, xb);
  gg_k<<<MROWS/64,256,0,stream>>>(xb, rs1,eg1, rs2,eg2,
                                  wg1_t, b_g1, wg2_t, s2);
  pn_k<<<NROWS/32,256,0,stream>>>(s2, rs1,eg1, rs2,eg2, b_g2,
                                  wfc1_t, b_fc1, wfc2_t, b_fc2, Zf, bdot);
  gram3_k<<<8224,256,0,stream>>>((const unsigned char*)Zf, P);   // 32896 UT tiles
  rloss_k<<<NROWS/32,256,0,stream>>>(P, bdot, (float*)d_out);
}

// Round 11
// 218.682 us; speedup vs baseline: 1.1589x; 1.1421x over previous
//
#include <hip/hip_runtime.h>
#include <hip/hip_bf16.h>
#include <math.h>

// GRACE-style graph contrastive loss, MI355X (gfx950).
// R25: kill the CSR build's duplicated atomic pass. R23/R24 showed fill's
// ~35-40us is intrinsic (contended fetch-add + scattered stores; immune to
// TLP/ILP shaping). So pay it ONCE: padded row slots (128/row, P(overflow)
// ~e^-81) let fill assign positions with the SAME atomic that counts degree.
// Histogram pass (512K contended atomics in setup_k) deleted; scan2_k
// deleted; setup_k = weight transpose only. Gathers read base=row*128,
// len=deg[row]. fill+mlp stay fused (R22-proven co-residency), fill blocks
// first. 8 kernels -> 6. Baseline: 247.1 (R22) / 249.8 (R24).

#define NROWS 8192
#define MROWS 16384
#define NEDGE 262144
#define ECAP 128            // padded slots per row (mean deg 32)

typedef __attribute__((ext_vector_type(8))) short bf16x8;
typedef __attribute__((ext_vector_type(4))) float f32x4;
typedef __attribute__((ext_vector_type(2))) float f32x2;
typedef __attribute__((ext_vector_type(8))) int i32x8;
typedef long long i64;

__device__ __forceinline__ short f2bf(float f){
  union { float f; unsigned u; } cv; cv.f = f;
  unsigned u = cv.u;
  unsigned r = (u + 0x7fffu + ((u >> 16) & 1u)) >> 16;  // RNE; inputs finite
  return (short)r;
}
__device__ __forceinline__ f32x4 mfma16(bf16x8 a, bf16x8 b, f32x4 c){
  return __builtin_amdgcn_mfma_f32_16x16x32_bf16(a, b, c, 0, 0, 0);
}
__device__ __forceinline__ float fexp2(float x){
#if __has_builtin(__builtin_amdgcn_exp2f)
  return __builtin_amdgcn_exp2f(x);
#else
  return exp2f(x);
#endif
}

// DPP row_shl add: lane i += lane(i+N) within each 16-lane row (0 beyond row
// edge via bound_ctrl). Chain {1,2,4,8}: lane 0 of each row accumulates the
// balanced tree ((v0+v1)+(v2+v3))+... == xor butterfly's lane-0 result.
template<int CTRL>
__device__ __forceinline__ float dpp_add(float v){
  int s = __builtin_amdgcn_update_dpp(0, __builtin_bit_cast(int, v),
                                      CTRL, 0xf, 0xf, true);
  return v + __builtin_bit_cast(float, s);
}
__device__ __forceinline__ float red16(float v){
  v = dpp_add<0x101>(v);   // row_shl:1
  v = dpp_add<0x102>(v);   // row_shl:2
  v = dpp_add<0x104>(v);   // row_shl:4
  v = dpp_add<0x108>(v);   // row_shl:8
  return v;
}

// ---- fp8 e4m3fn pack (RNE) ----
__device__ unsigned char f2e4m3_sw(float f){
  float a = fabsf(f);
  unsigned s = (__float_as_uint(f)>>24)&0x80u;
  if (!(a>0.f)) return (unsigned char)s;
  if (a>448.f) a=448.f;
  int e; frexpf(a,&e);
  int eff=e-1;
  unsigned code;
  if (eff<-6){
    float q=rintf(a*512.f);
    code=(unsigned)q; if(code>7)code=7;
  } else {
    float q=rintf(a*exp2f((float)(3-eff)));
    unsigned mant=(unsigned)q;
    if(mant>=16){mant=8;eff++;}
    if(eff>8) return (unsigned char)(s|0x7e);
    code=((unsigned)(eff+7)<<3)|(mant-8);
  }
  return (unsigned char)(s|code);
}
__device__ __forceinline__ unsigned short pack2fp8(float a, float b){
#if __has_builtin(__builtin_amdgcn_cvt_pk_fp8_f32)
  int v = __builtin_amdgcn_cvt_pk_fp8_f32(a, b, 0, false);
  return (unsigned short)(v & 0xffff);
#else
  return (unsigned short)((unsigned)f2e4m3_sw(a) | ((unsigned)f2e4m3_sw(b)<<8));
#endif
}

// ---- setup: weight transpose+bf16 only (histogram pass deleted in R25) ----
struct WtArgs {
  const float* src[6];
  short* dst[6];
  int K[6], N[6];
  int off[7];
  int nwt;
};
__global__ void setup_k(WtArgs a){
  int i = blockIdx.x*256 + threadIdx.x;
  if (i >= a.off[6]) return;
  int s = 0;
  #pragma unroll
  for (int j=1;j<6;j++) if (i >= a.off[j]) s=j;
  int l = i - a.off[s];
  int K=a.K[s], N=a.N[s];
  int k=l/N, n=l-k*N;
  a.dst[s][(long)n*K+k] = f2bf(a.src[s][l]);
}

// ---- fm2_k: padded-slot edge fill (blocks 0..2047; deg counted by the SAME
// atomic that assigns the slot) fused with mlp12 (blocks 2048..2559). ----
__global__ __launch_bounds__(256) void fm2_k(const float* __restrict__ F0, const float* __restrict__ F1,
    const short* __restrict__ Wa, const float* __restrict__ ba,
    const short* __restrict__ Wb, const float* __restrict__ bb, short* __restrict__ xb,
    const int* __restrict__ ei1, const float* __restrict__ w1, int* __restrict__ deg1,
    int2* __restrict__ eg1,
    const int* __restrict__ ei2, const float* __restrict__ w2, int* __restrict__ deg2,
    int2* __restrict__ eg2){
  __shared__ short As[32*520];   // 32x512 bf16, +8 pad
  __shared__ short a1s[32*72];   // 32x64 bf16, +8 pad
  const int tid = threadIdx.x;
  if (blockIdx.x < 2*(NEDGE/256)){
    // ---- fill role: one edge/thread; slot = row*ECAP + fetch_add(deg) ----
    int b = blockIdx.x;
    bool g2 = (b >= NEDGE/256);
    const int* ei = g2 ? ei2 : ei1;
    const float* w = g2 ? w2 : w1;
    int* deg = g2 ? deg2 : deg1;
    int2* eg = g2 ? eg2 : eg1;
    int e = (b % (NEDGE/256))*256 + tid;
    int r = ei[e];
    int c = ei[NEDGE + e];
    float wv = w[e];
    int p = atomicAdd(&deg[r], 1);
    eg[(long)r*ECAP + p] = make_int2(c, __float_as_int(wv));
    return;
  }
  // ---- mlp12 role: xb[M,32] = (relu(feat@Wa+ba))@Wb+bb, 32 rows/block ----
  const int m0 = (blockIdx.x - 2*(NEDGE/256))*32;
  const float* F = (m0 < NROWS) ? (F0 + (long)m0*512) : (F1 + (long)(m0-NROWS)*512);
  {
    float4 st[16];
    #pragma unroll
    for (int i=0;i<16;i++) st[i] = *(const float4*)(F + (long)(i*256+tid)*4);
    #pragma unroll
    for (int i=0;i<16;i++){
      int idx = i*256+tid, row = idx>>7, c4 = idx&127;
      unsigned lo = (unsigned)(unsigned short)f2bf(st[i].x) | ((unsigned)(unsigned short)f2bf(st[i].y)<<16);
      unsigned hi = (unsigned)(unsigned short)f2bf(st[i].z) | ((unsigned)(unsigned short)f2bf(st[i].w)<<16);
      uint2 o = {lo, hi};
      *(uint2*)&As[row*520 + c4*4] = o;
    }
  }
  __syncthreads();
  const int wave = tid>>6, lane = tid&63, quad = lane>>4, cl = lane&15;
  f32x4 zero = {0.f,0.f,0.f,0.f};
  {
    // stage1: 32 rows (MT=2) x 16 cols per wave, K=512
    const int wno = wave*16;
    f32x4 acc[2] = {zero, zero};
    #pragma unroll
    for (int kc=0;kc<16;kc++){
      const int ko = kc*32 + quad*8;
      bf16x8 a0 = *(const bf16x8*)&As[(cl)*520 + ko];
      bf16x8 a1 = *(const bf16x8*)&As[(16+cl)*520 + ko];
      bf16x8 b = *(const bf16x8*)(Wa + (long)(wno + cl)*512 + ko);
      acc[0] = mfma16(a0, b, acc[0]);
      acc[1] = mfma16(a1, b, acc[1]);
    }
    int col = wno + cl;
    float bv = ba[col];
    #pragma unroll
    for (int mt=0;mt<2;mt++)
      #pragma unroll
      for (int r=0;r<4;r++)
        a1s[(mt*16 + quad*4 + r)*72 + col] = f2bf(fmaxf(acc[mt][r] + bv, 0.f));
  }
  __syncthreads();
  if (wave < 2){
    // stage2: wave w -> rows w*16..+15, full 32 cols (NT=2), K=64
    f32x4 acc2[2] = {zero, zero};
    #pragma unroll
    for (int kc=0;kc<2;kc++){
      const int ko = kc*32 + quad*8;
      bf16x8 a = *(const bf16x8*)&a1s[(wave*16+cl)*72 + ko];
      #pragma unroll
      for (int nt=0;nt<2;nt++){
        bf16x8 b = *(const bf16x8*)(Wb + (long)(nt*16 + cl)*64 + ko);
        acc2[nt] = mfma16(a, b, acc2[nt]);
      }
    }
    #pragma unroll
    for (int nt=0;nt<2;nt++){
      int col = nt*16 + cl;
      float bv = bb[col];
      #pragma unroll
      for (int r=0;r<4;r++)
        xb[(long)(m0 + wave*16 + quad*4 + r)*32 + col] = f2bf(acc2[nt][r] + bv);
    }
  }
}

// ---- gather helpers (packed int2 edges: x=col, y=weight bits) ----
__device__ __forceinline__ void acc8(float* acc, int4 v, float f){
  const unsigned* u = (const unsigned*)&v;
  #pragma unroll
  for (int i=0;i<4;i++){
    union{unsigned x; float y;} lo, hi;
    lo.x = u[i] << 16;
    hi.x = u[i] & 0xffff0000u;
    acc[2*i]   = fmaf(f, lo.y, acc[2*i]);
    acc[2*i+1] = fmaf(f, hi.y, acc[2*i+1]);
  }
}
template<int C>
__device__ __forceinline__ void gather_row(float* acc, const short* sb,
                                           const int2* eg, int s, int e){
  int k = s;
  for (; k+16 <= e; k+=16){
    int2 cw[16]; int4 v[16];
    #pragma unroll
    for (int u=0;u<16;u++) cw[u] = eg[k+u];
    #pragma unroll
    for (int u=0;u<16;u++) v[u] = *(const int4*)(sb + (long)cw[u].x*C);
    #pragma unroll
    for (int u=0;u<16;u++) acc8(acc, v[u], __int_as_float(cw[u].y));
  }
  for (; k+4 <= e; k+=4){
    int2 c0=eg[k], c1=eg[k+1], c2=eg[k+2], c3=eg[k+3];
    int4 v0 = *(const int4*)(sb + (long)c0.x*C);
    int4 v1 = *(const int4*)(sb + (long)c1.x*C);
    int4 v2 = *(const int4*)(sb + (long)c2.x*C);
    int4 v3 = *(const int4*)(sb + (long)c3.x*C);
    acc8(acc,v0,__int_as_float(c0.y)); acc8(acc,v1,__int_as_float(c1.y));
    acc8(acc,v2,__int_as_float(c2.y)); acc8(acc,v3,__int_as_float(c3.y));
  }
  for (; k < e; k++){
    int2 c0 = eg[k];
    int4 v0 = *(const int4*)(sb + (long)c0.x*C);
    acc8(acc,v0,__int_as_float(c0.y));
  }
}

// ---- gg_k: gather32 (adj@xb -> LDS) + g34 (relu(ax@Wg1+bg1)@Wg2 -> s2) ----
__global__ __launch_bounds__(256) void gg_k(const short* __restrict__ xb,
    const int* __restrict__ deg1, const int2* __restrict__ eg1,
    const int* __restrict__ deg2, const int2* __restrict__ eg2,
    const short* __restrict__ Wg1, const float* __restrict__ bg1,
    const short* __restrict__ Wg2, short* __restrict__ s2){
  __shared__ short axs[64*40];    // gathered ax tile (pad 8)
  __shared__ short hbs[64*264];   // relu(ax@Wg1+b) tile (pad 8)
  const int tid = threadIdx.x;
  const int m0 = blockIdx.x*64;
  {
    const int g = tid & 3, sub = tid >> 2;
    const int row = m0 + sub;
    const int* deg; const int2* eg; int soff, lr;
    if (row < NROWS){ deg=deg1; eg=eg1; soff=0; lr=row; }
    else            { deg=deg2; eg=eg2; soff=NROWS; lr=row-NROWS; }
    const short* sb = xb + (long)soff*32 + g*8;
    float acc[8];
    #pragma unroll
    for (int j=0;j<8;j++) acc[j] = 0.f;
    gather_row<32>(acc, sb, eg + (long)lr*ECAP, 0, deg[lr]);
    int4 ov;
    unsigned* ou = (unsigned*)&ov;
    #pragma unroll
    for (int i=0;i<4;i++)
      ou[i] = (unsigned)(unsigned short)f2bf(acc[2*i]) | ((unsigned)(unsigned short)f2bf(acc[2*i+1])<<16);
    *(int4*)&axs[sub*40 + g*8] = ov;
  }
  __syncthreads();
  const int wave = tid>>6, lane = tid&63, quad = lane>>4, cl = lane&15;
  f32x4 zero = {0.f,0.f,0.f,0.f};
  {
    const int wno = wave*64;
    f32x4 acc[4][4];
    #pragma unroll
    for (int i=0;i<4;i++)
      #pragma unroll
      for (int j=0;j<4;j++) acc[i][j]=zero;
    const int ko = quad*8;
    bf16x8 a[4], b[4];
    #pragma unroll
    for (int mt=0;mt<4;mt++)
      a[mt] = *(const bf16x8*)&axs[(mt*16+cl)*40 + ko];
    #pragma unroll
    for (int nt=0;nt<4;nt++)
      b[nt] = *(const bf16x8*)(Wg1 + (long)(wno + nt*16 + cl)*32 + ko);
    #pragma unroll
    for (int mt=0;mt<4;mt++)
      #pragma unroll
      for (int nt=0;nt<4;nt++)
        acc[mt][nt] = mfma16(a[mt], b[nt], acc[mt][nt]);
    #pragma unroll
    for (int nt=0;nt<4;nt++){
      int col = wno + nt*16 + cl;
      float bv = bg1[col];
      #pragma unroll
      for (int mt=0;mt<4;mt++)
        #pragma unroll
        for (int r=0;r<4;r++)
          hbs[(mt*16 + quad*4 + r)*264 + col] = f2bf(fmaxf(acc[mt][nt][r] + bv, 0.f));
    }
  }
  __syncthreads();
  {
    const int wno = wave*32;
    f32x4 acc[4][2];
    #pragma unroll
    for (int i=0;i<4;i++){ acc[i][0]=zero; acc[i][1]=zero; }
    #pragma unroll
    for (int kc=0;kc<8;kc++){
      const int ko = kc*32 + quad*8;
      bf16x8 a[4], b[2];
      #pragma unroll
      for (int mt=0;mt<4;mt++)
        a[mt] = *(const bf16x8*)&hbs[(mt*16+cl)*264 + ko];
      #pragma unroll
      for (int nt=0;nt<2;nt++)
        b[nt] = *(const bf16x8*)(Wg2 + (long)(wno + nt*16 + cl)*256 + ko);
      #pragma unroll
      for (int mt=0;mt<4;mt++)
        #pragma unroll
        for (int nt=0;nt<2;nt++)
          acc[mt][nt] = mfma16(a[mt], b[nt], acc[mt][nt]);
    }
    #pragma unroll
    for (int mt=0;mt<4;mt++)
      #pragma unroll
      for (int nt=0;nt<2;nt++){
        int col = wno + nt*16 + cl;
        #pragma unroll
        for (int r=0;r<4;r++)
          s2[(long)(m0 + mt*16 + quad*4 + r)*128 + col] = f2bf(acc[mt][nt][r]);
      }
  }
}

// ---- pn_k: layer-2 aggregation (gathered in-block) + proj1(elu) +
// proj2 + normalize + fp8-quantize, PAIR-ROW blocks. ----
__global__ __launch_bounds__(256) void pn_k(const short* __restrict__ s2,
    const int* __restrict__ deg1, const int2* __restrict__ eg1,
    const int* __restrict__ deg2, const int2* __restrict__ eg2,
    const float* __restrict__ bg2,
    const short* __restrict__ Wf1, const float* __restrict__ bf1,
    const short* __restrict__ Wf2, const float* __restrict__ bf2,
    unsigned short* __restrict__ Zf, float* __restrict__ bdot){
  __shared__ short hs[64*136];
  __shared__ short t2s[64*72];
  __shared__ float zs[64*132];
  __shared__ float sp[4][64];
  __shared__ float dp[4][32];
  __shared__ float rnS[64];
  const float SQKE = 1.6986436f;   // sqrt(2*log2(e))
  const int tid = threadIdx.x;
  const int wave = tid>>6, lane = tid&63, quad = lane>>4, cl = lane&15;
  const int m0h = blockIdx.x*32;
  {
    // gather 64 rows into hs: rows 0..31 = graph1, rows 32..63 = graph2.
    const int g = tid & 15, sub = tid >> 4;
    #pragma unroll 1
    for (int pass=0; pass<4; pass++){
      int hrow = pass*16 + sub;
      int lr = m0h + (hrow & 31);
      const int* deg; const int2* eg; long soff;
      if (hrow < 32){ deg=deg1; eg=eg1; soff=0; }
      else          { deg=deg2; eg=eg2; soff=NROWS; }
      const short* sb = s2 + soff*128 + g*8;
      float acc[8];
      #pragma unroll
      for (int j=0;j<8;j++) acc[j] = bg2[g*8+j];
      gather_row<128>(acc, sb, eg + (long)lr*ECAP, 0, deg[lr]);
      int4 ov;
      unsigned* ou = (unsigned*)&ov;
      #pragma unroll
      for (int i=0;i<4;i++)
        ou[i] = (unsigned)(unsigned short)f2bf(acc[2*i]) | ((unsigned)(unsigned short)f2bf(acc[2*i+1])<<16);
      *(int4*)&hs[hrow*136 + g*8] = ov;
    }
  }
  __syncthreads();
  f32x4 zero = {0.f,0.f,0.f,0.f};
  {
    // proj1: NN=64, K=128, elu -> t2s
    const int wno = wave*16;
    f32x4 acc[4];
    #pragma unroll
    for (int i=0;i<4;i++) acc[i]=zero;
    #pragma unroll
    for (int kc=0;kc<4;kc++){
      const int ko = kc*32 + quad*8;
      bf16x8 a[4], b;
      #pragma unroll
      for (int mt=0;mt<4;mt++)
        a[mt] = *(const bf16x8*)&hs[(mt*16+cl)*136 + ko];
      b = *(const bf16x8*)(Wf1 + (long)(wno + cl)*128 + ko);
      #pragma unroll
      for (int mt=0;mt<4;mt++) acc[mt] = mfma16(a[mt], b, acc[mt]);
    }
    int col = wno + cl;
    float bv = bf1[col];
    #pragma unroll
    for (int mt=0;mt<4;mt++)
      #pragma unroll
      for (int r=0;r<4;r++){
        float v = acc[mt][r] + bv;
        v = (v > 0.f) ? v : expm1f(v);
        t2s[(mt*16 + quad*4 + r)*72 + col] = f2bf(v);
      }
  }
  __syncthreads();
  {
    // proj2: NN=128, K=64 -> zs (fp32)
    const int wno = wave*32;
    f32x4 acc[4][2];
    #pragma unroll
    for (int i=0;i<4;i++){ acc[i][0]=zero; acc[i][1]=zero; }
    #pragma unroll
    for (int kc=0;kc<2;kc++){
      const int ko = kc*32 + quad*8;
      bf16x8 a[4], b[2];
      #pragma unroll
      for (int mt=0;mt<4;mt++)
        a[mt] = *(const bf16x8*)&t2s[(mt*16+cl)*72 + ko];
      #pragma unroll
      for (int nt=0;nt<2;nt++)
        b[nt] = *(const bf16x8*)(Wf2 + (long)(wno + nt*16 + cl)*64 + ko);
      #pragma unroll
      for (int mt=0;mt<4;mt++)
        #pragma unroll
        for (int nt=0;nt<2;nt++)
          acc[mt][nt] = mfma16(a[mt], b[nt], acc[mt][nt]);
    }
    #pragma unroll
    for (int mt=0;mt<4;mt++)
      #pragma unroll
      for (int nt=0;nt<2;nt++){
        int col = wno + nt*16 + cl;
        float bv = bf2[col];
        #pragma unroll
        for (int r=0;r<4;r++)
          zs[(mt*16 + quad*4 + r)*132 + col] = acc[mt][nt][r] + bv;
      }
  }
  __syncthreads();
  {
    int row = tid & 63, qtr = tid >> 6;
    const float* zr = &zs[row*132 + qtr*32];
    float s = 0.f;
    #pragma unroll 8
    for (int c=0;c<32;c++) s += zr[c]*zr[c];
    sp[qtr][row] = s;
    if (row < 32){
      const float* zb_ = &zs[(row+32)*132 + qtr*32];
      float d = 0.f;
      #pragma unroll 8
      for (int c=0;c<32;c++) d += zr[c]*zb_[c];
      dp[qtr][row] = d;
    }
  }
  __syncthreads();
  if (tid < 64){
    float ssq = sp[0][tid]+sp[1][tid]+sp[2][tid]+sp[3][tid];
    rnS[tid] = 1.f / fmaxf(sqrtf(ssq), 1e-12f);
  }
  __syncthreads();
  if (tid < 32){
    float dot = dp[0][tid]+dp[1][tid]+dp[2][tid]+dp[3][tid];
    bdot[m0h + tid] = dot * rnS[tid] * rnS[tid+32];
  }
  {
    // fp8*sqrt(KE) quantize into K=128 f8f6f4 fragment-order Zf.
    int lr = tid >> 2;
    int grow = (lr < 32) ? (m0h + lr) : (NROWS + m0h + lr - 32);
    float s = rnS[lr] * SQKE;
    int p0 = (tid & 3)*16;
    long gbase = (long)(grow>>4)*1024 + (long)(grow&15)*16 + (long)(p0>>4)*256;
    #pragma unroll
    for (int pp=0;pp<16;pp++){
      int p = p0 + pp;
      Zf[gbase + pp] = pack2fp8(zs[lr*132 + 2*p]*s, zs[lr*132 + 2*p + 1]*s);
    }
  }
}

// ---- symmetric exp-Gram partials (R18 form: single tile/wave, MX K=128
// MFMA scale=1.0, strip pipeline, DPP row_shl reduce; VGPR 60, no spill).
__global__ __launch_bounds__(256,4) void gram3_k(const unsigned char* __restrict__ Zf,
                                                 float* __restrict__ P){
  __shared__ float srow[4][64];
  __shared__ float scol[4][64];
  const int wave = threadIdx.x>>6, lane = threadIdx.x&63;
  const int t = blockIdx.x*4 + wave;           // UT tile index, T=256
  int ti = (int)((513.0f - sqrtf(513.0f*513.0f - 8.0f*(float)t))*0.5f);
  while ((ti+1)*256 - ((ti+1)*ti)/2 <= t) ti++;
  while (ti*256 - (ti*(ti-1))/2 > t) ti--;
  const int tj = ti + (t - (ti*256 - (ti*(ti-1))/2));
  // 64-row tile = 4 groups x 2048B; lane reads 32 contiguous K-bytes
  const unsigned char* za = Zf + (long)ti*8192 + lane*32;
  const unsigned char* zb = Zf + (long)tj*8192 + lane*32;
  const int quad = lane>>4, cl = lane&15;

  f32x4 zero = {0.f,0.f,0.f,0.f};
  f32x2 z2 = {0.f,0.f};
  f32x2 cs[4] = {z2,z2,z2,z2};

  // all B fragments resident: Bf[nt] (v8i32 each)
  i32x8 Bf[4];
  #pragma unroll
  for (int nt=0;nt<4;nt++)
    Bf[nt] = *(const i32x8*)(zb + nt*2048);

  // A double-buffer: strip mt lives in Ab[mt&1]
  i32x8 Ab[2];
  Ab[0] = *(const i32x8*)(za);
  Ab[1] = *(const i32x8*)(za + 2048);

  // exp + row-sum reduce of one 16-row strip; DPP row_shl tree (lane cl==0
  // result bit-identical to the xor butterfly's).
  auto exprow = [&](const f32x4* ar, int mt){
    f32x2 r01 = z2, r23 = z2;
    #pragma unroll
    for (int nt=0;nt<4;nt++){
      f32x4 v = ar[nt];
      float e0 = fexp2(v[0]), e1 = fexp2(v[1]);
      float e2 = fexp2(v[2]), e3 = fexp2(v[3]);
      f32x2 p01 = {e0,e1}, p23 = {e2,e3};
      r01 += p01; r23 += p23;
      cs[nt] += p01; cs[nt] += p23;
    }
    float s0 = red16(r01.x);
    float s1 = red16(r01.y);
    float s2 = red16(r23.x);
    float s3 = red16(r23.y);
    if (cl==0){
      f32x4 rv = {s0, s1, s2, s3};
      *(f32x4*)&srow[wave][mt*16 + quad*4] = rv;
    }
  };

  const int SC1 = 0x7F;   // e8m0 scale = 2^0
  f32x4 acc2[2][4];
  // strip 0: one K=128 MFMA per nt
  #pragma unroll
  for (int nt=0;nt<4;nt++)
    acc2[0][nt] = __builtin_amdgcn_mfma_scale_f32_16x16x128_f8f6f4(
        Ab[0], Bf[nt], zero, 0, 0, 0, SC1, 0, SC1);
  // strips 1..3: prefetch A, issue MFMAs, exp previous strip underneath
  #pragma unroll
  for (int mt=1; mt<4; mt++){
    const int cur = mt&1, prv = cur^1;
    if (mt<3)
      Ab[prv] = *(const i32x8*)(za + (mt+1)*2048);
    #pragma unroll
    for (int nt=0;nt<4;nt++)
      acc2[cur][nt] = __builtin_amdgcn_mfma_scale_f32_16x16x128_f8f6f4(
          Ab[cur], Bf[nt], zero, 0, 0, 0, SC1, 0, SC1);
    exprow(&acc2[prv][0], mt-1);
  }
  exprow(&acc2[1][0], 3);

  __threadfence_block();
  P[((long)ti*256 + tj)*64 + lane] = srow[wave][lane];
  if (ti != tj){
    #pragma unroll
    for (int nt=0;nt<4;nt++){
      float s = cs[nt].x + cs[nt].y;
      s += __shfl_xor(s,16); s += __shfl_xor(s,32);
      if (quad==0) scol[wave][nt*16 + cl] = s;
    }
    __threadfence_block();
    P[((long)tj*256 + ti)*64 + lane] = scol[wave][lane];
  }
}

// ---- fused final reduce + loss (256 blocks x 32 rows, 8 chunk-groups) ----
__global__ __launch_bounds__(256) void rloss_k(const float* __restrict__ P,
                                               const float* __restrict__ bdot,
                                               float* __restrict__ out){
  __shared__ float ps[8][32][2];
  const float E2 = 7.3890560989306495f;  // exp(2) = diag(refl)
  int t = threadIdx.x;
  int rloc = t & 31, grp = t >> 5;
  int i = blockIdx.x*32 + rloc;          // 0..8191
  int j = i + NROWS;
  const float* p1 = P + (long)(i>>6)*256*64 + (long)grp*32*64 + (i&63);
  const float* p2 = P + (long)(j>>6)*256*64 + (long)grp*32*64 + (j&63);
  float s1 = 0.f, s2 = 0.f;
  #pragma unroll 8
  for (int b=0;b<32;b++){ s1 += p1[b*64]; s2 += p2[b*64]; }
  ps[grp][rloc][0] = s1;
  ps[grp][rloc][1] = s2;
  __syncthreads();
  if (t < 64){
    float term = 0.f;
    if (t < 32){
      float a1 = 0.f, a2 = 0.f;
      #pragma unroll
      for (int g=0; g<8; g++){ a1 += ps[g][t][0]; a2 += ps[g][t][1]; }
      int ii = blockIdx.x*32 + t;
      float lb = 2.f * bdot[ii];
      term = 0.5f * ((logf(a1 - E2) - lb) + (logf(a2 - E2) - lb));
    }
    #pragma unroll
    for (int m=1; m<64; m<<=1) term += __shfl_xor(term, m);
    if (t==0) atomicAdd(out, term / (float)NROWS);
  }
}

extern "C" void kernel_launch(void* const* d_in, const int* in_sizes, int n_in,
                              void* d_out, int out_size, void* d_ws, size_t ws_size,
                              hipStream_t stream){
  const float* feat1 = (const float*)d_in[0];
  const float* feat2 = (const float*)d_in[1];
  const int*   ei1   = (const int*)d_in[2];
  const float* w1    = (const float*)d_in[3];
  const int*   ei2   = (const int*)d_in[4];
  const float* w2    = (const float*)d_in[5];
  const float* w_l1a = (const float*)d_in[6];
  const float* b_l1a = (const float*)d_in[7];
  const float* w_l1b = (const float*)d_in[8];
  const float* b_l1b = (const float*)d_in[9];
  const float* w_g1  = (const float*)d_in[10];
  const float* b_g1  = (const float*)d_in[11];
  const float* w_g2  = (const float*)d_in[12];
  const float* b_g2  = (const float*)d_in[13];
  const float* w_fc1 = (const float*)d_in[14];
  const float* b_fc1 = (const float*)d_in[15];
  const float* w_fc2 = (const float*)d_in[16];
  const float* b_fc2 = (const float*)d_in[17];

  float* P = (float*)d_ws;          // 16.8MB partials at ws base
  char* base = (char*)d_ws;
  size_t off = (size_t)17<<20;      // live buffers beyond P
  auto alloc = [&](size_t bytes)->void*{
    void* r = base + off;
    off = (off + bytes + 255) & ~(size_t)255;
    return r;
  };
  short* xb   = (short*)alloc((size_t)MROWS*32*2);
  short* s2   = (short*)alloc((size_t)MROWS*128*2);
  short* wl1a_t = (short*)alloc(512*64*2);
  short* wl1b_t = (short*)alloc(64*32*2);
  short* wg1_t  = (short*)alloc(32*256*2);
  short* wg2_t  = (short*)alloc(256*128*2);
  short* wfc1_t = (short*)alloc(128*64*2);
  short* wfc2_t = (short*)alloc(64*128*2);
  unsigned short* Zf = (unsigned short*)alloc((size_t)MROWS*128);   // fragment-order fp8
  int*   deg1 = (int*)alloc(NROWS*4);                               // zeroed pair
  int*   deg2 = (int*)alloc(NROWS*4);
  int2*  eg1 = (int2*)alloc((size_t)NROWS*ECAP*8);   // padded {col, weight-bits}
  int2*  eg2 = (int2*)alloc((size_t)NROWS*ECAP*8);
  float* bdot  = (float*)alloc(NROWS*4);

  hipMemsetAsync(deg1, 0, (size_t)2*NROWS*4, stream);
  hipMemsetAsync(d_out, 0, sizeof(float), stream);

  WtArgs wa;
  wa.src[0]=w_l1a; wa.dst[0]=wl1a_t; wa.K[0]=512; wa.N[0]=64;
  wa.src[1]=w_l1b; wa.dst[1]=wl1b_t; wa.K[1]=64;  wa.N[1]=32;
  wa.src[2]=w_g1;  wa.dst[2]=wg1_t;  wa.K[2]=32;  wa.N[2]=256;
  wa.src[3]=w_g2;  wa.dst[3]=wg2_t;  wa.K[3]=256; wa.N[3]=128;
  wa.src[4]=w_fc1; wa.dst[4]=wfc1_t; wa.K[4]=128; wa.N[4]=64;
  wa.src[5]=w_fc2; wa.dst[5]=wfc2_t; wa.K[5]=64;  wa.N[5]=128;
  wa.off[0]=0;
  for (int i=0;i<6;i++) wa.off[i+1] = wa.off[i] + wa.K[i]*wa.N[i];
  wa.nwt = (wa.off[6]+255)/256;

  setup_k<<<wa.nwt,256,0,stream>>>(wa);
  fm2_k<<<2*(NEDGE/256) + MROWS/32,256,0,stream>>>(feat1, feat2, wl1a_t, b_l1a,
      wl1b_t, b_l1b, xb,
      ei1, w1, deg1, eg1,
      ei2, w2, deg2, eg2);
  gg_k<<<MROWS/64,256,0,stream>>>(xb, deg1,eg1, deg2,eg2,
                                  wg1_t, b_g1, wg2_t, s2);
  pn_k<<<NROWS/32,256,0,stream>>>(s2, deg1,eg1, deg2,eg2, b_g2,
                                  wfc1_t, b_fc1, wfc2_t, b_fc2, Zf, bdot);
  gram3_k<<<8224,256,0,stream>>>((const unsigned char*)Zf, P);   // 32896 UT tiles
  rloss_k<<<NROWS/32,256,0,stream>>>(P, bdot, (float*)d_out);
}